// Round 3
// baseline (4993.677 us; speedup 1.0000x reference)
//
#include <hip/hip_runtime.h>
#include <hip/hip_bf16.h>
#include <math.h>

// Problem constants (from reference)
#define B_    2
#define S_    2048
#define DIM_  2048
#define H_    16
#define NOPE_ 128
#define ROPE_ 64
#define VDIM_ 128
#define QR_   1024
#define KVR_  512
#define TOK_  (B_ * S_)   // 4096 token rows

// ---------------------------------------------------------------------------
// GEMM: C[M x N] = A[M x K] @ B[N x K]^T   (both row-major, K contiguous)
// 64x64 tile, BK=32, 256 threads, 4x4 accumulators/thread, padded LDS.
// ---------------------------------------------------------------------------
#define BM 64
#define BN 64
#define BK 32

__global__ __launch_bounds__(256) void gemm_bt(const float* __restrict__ A,
                                               const float* __restrict__ Bm,
                                               float* __restrict__ C,
                                               int M, int N, int K) {
  __shared__ float As[BM][BK + 1];   // +1 pad: breaks 32-bank aliasing
  __shared__ float Bs[BN][BK + 1];
  const int tid = threadIdx.x;
  const int m0 = blockIdx.y * BM;
  const int n0 = blockIdx.x * BN;
  const int tx = tid & 15;
  const int ty = tid >> 4;
  const int lr = tid >> 3;          // 0..31 (staging row)
  const int lc = (tid & 7) << 2;    // 0,4,...,28 (staging col, float4)
  float acc[4][4] = {};

  for (int k0 = 0; k0 < K; k0 += BK) {
#pragma unroll
    for (int i = 0; i < 2; ++i) {
      const int r = lr + i * 32;
      float4 va = *(const float4*)(A + (size_t)(m0 + r) * K + k0 + lc);
      As[r][lc] = va.x; As[r][lc + 1] = va.y; As[r][lc + 2] = va.z; As[r][lc + 3] = va.w;
      float4 vb = *(const float4*)(Bm + (size_t)(n0 + r) * K + k0 + lc);
      Bs[r][lc] = vb.x; Bs[r][lc + 1] = vb.y; Bs[r][lc + 2] = vb.z; Bs[r][lc + 3] = vb.w;
    }
    __syncthreads();
#pragma unroll
    for (int kk = 0; kk < BK; ++kk) {
      float a[4], b[4];
#pragma unroll
      for (int i = 0; i < 4; ++i) a[i] = As[ty * 4 + i][kk];
#pragma unroll
      for (int j = 0; j < 4; ++j) b[j] = Bs[tx * 4 + j][kk];
#pragma unroll
      for (int i = 0; i < 4; ++i)
#pragma unroll
        for (int j = 0; j < 4; ++j) acc[i][j] = fmaf(a[i], b[j], acc[i][j]);
    }
    __syncthreads();
  }
#pragma unroll
  for (int i = 0; i < 4; ++i)
#pragma unroll
    for (int j = 0; j < 4; ++j)
      C[(size_t)(m0 + ty * 4 + i) * N + n0 + tx * 4 + j] = acc[i][j];
}

// ---------------------------------------------------------------------------
// RMSNorm in place over rows of length n (fp32, matches JAX fp32 math)
// ---------------------------------------------------------------------------
__global__ __launch_bounds__(256) void rmsnorm_inplace(float* __restrict__ x,
                                                       const float* __restrict__ w,
                                                       int n) {
  __shared__ float red[256];
  const int row = blockIdx.x;
  float* p = x + (size_t)row * n;
  float s = 0.f;
  for (int i = threadIdx.x; i < n; i += 256) { float v = p[i]; s += v * v; }
  red[threadIdx.x] = s;
  __syncthreads();
  for (int off = 128; off > 0; off >>= 1) {
    if (threadIdx.x < off) red[threadIdx.x] += red[threadIdx.x + off];
    __syncthreads();
  }
  const float inv = rsqrtf(red[0] / (float)n + 1e-6f);
  for (int i = threadIdx.x; i < n; i += 256) p[i] = p[i] * inv * w[i];
}

// ---------------------------------------------------------------------------
// Interleaved RoPE in place. Layout: (rows, heads*64); pos = row % S.
// angle = pos * 10000^(-pair/32); out[2i]=x1*c-x2*s, out[2i+1]=x1*s+x2*c
// ---------------------------------------------------------------------------
__global__ void rope_inplace(float* __restrict__ x, int heads, int total_pairs) {
  int idx = blockIdx.x * blockDim.x + threadIdx.x;
  if (idx >= total_pairs) return;
  const int i = idx & 31;                 // pair index 0..31
  const int h = (idx >> 5) % heads;
  const int row = idx / (32 * heads);
  const int pos = row & (S_ - 1);         // row % S (S is pow2)
  // 10000^(-i/32) = exp(-ln(10000) * i / 32)
  const float freq = expf(-9.210340371976184f * (float)i / 32.0f);
  const float ang = (float)pos * freq;
  const float c = cosf(ang), sn = sinf(ang);
  float* p = x + ((size_t)row * heads + h) * 64 + 2 * i;
  const float x1 = p[0], x2 = p[1];
  p[0] = x1 * c - x2 * sn;
  p[1] = x1 * sn + x2 * c;
}

// ---------------------------------------------------------------------------
// Flash attention (causal, online softmax), fp32.
// Q: q_nope (tok, H*128) + q_pe (tok, H*64);  K/V from kv_up (tok, H*256)
// [cols h*256+0..127 = k_nope, +128..255 = v];  k_rope (tok, 64) shared.
// Block: 256 threads, TQ=32 queries, TK=16 keys/tile.
// Each thread owns O[row=tid/8][16 cols at (tid%8)*16].
// ---------------------------------------------------------------------------
#define TQ 32
#define TK 16

__global__ __launch_bounds__(256) void flash_attn(const float* __restrict__ q_nope,
                                                  const float* __restrict__ q_pe,
                                                  const float* __restrict__ kv_up,
                                                  const float* __restrict__ k_rope,
                                                  float* __restrict__ attn_o) {
  __shared__ float Qn[TQ][NOPE_ + 4];
  __shared__ float Qp[TQ][ROPE_ + 4];
  __shared__ float Kn[TK][NOPE_ + 4];
  __shared__ float Kr[TK][ROPE_ + 4];
  __shared__ float Vs[TK][VDIM_ + 4];
  __shared__ float Ps[TQ][TK];
  __shared__ float row_m[TQ], row_l[TQ], row_a[TQ];

  const int tid = threadIdx.x;
  const int q0 = blockIdx.x * TQ;
  const int h = blockIdx.y;
  const int b = blockIdx.z;
  const size_t tok0 = (size_t)b * S_;

  // Stage Q tile once (float4 units, coalesced)
  for (int u = tid; u < TQ * (NOPE_ / 4); u += 256) {
    const int r = u / (NOPE_ / 4), c = (u % (NOPE_ / 4)) * 4;
    *(float4*)&Qn[r][c] =
        *(const float4*)(q_nope + (tok0 + q0 + r) * (size_t)(H_ * NOPE_) + h * NOPE_ + c);
  }
  for (int u = tid; u < TQ * (ROPE_ / 4); u += 256) {
    const int r = u / (ROPE_ / 4), c = (u % (ROPE_ / 4)) * 4;
    *(float4*)&Qp[r][c] =
        *(const float4*)(q_pe + (tok0 + q0 + r) * (size_t)(H_ * ROPE_) + h * ROPE_ + c);
  }
  if (tid < TQ) { row_m[tid] = -3.0e38f; row_l[tid] = 0.f; }

  const int orow = tid >> 3;         // 0..31
  const int oc0 = (tid & 7) << 4;    // 0,16,...,112
  float o[16];
#pragma unroll
  for (int j = 0; j < 16; ++j) o[j] = 0.f;

  const float scale = 0.07216878364870323f;  // 1/sqrt(192)
  const int ktmax = (q0 + TQ - 1) / TK;

  for (int kt = 0; kt <= ktmax; ++kt) {
    const int k0 = kt * TK;
    __syncthreads();  // previous iter's Ps/Vs reads done before overwrite (also covers Q staging on kt=0)
    for (int u = tid; u < TK * (NOPE_ / 4); u += 256) {
      const int r = u / (NOPE_ / 4), c = (u % (NOPE_ / 4)) * 4;
      *(float4*)&Kn[r][c] = *(const float4*)(
          kv_up + (tok0 + k0 + r) * (size_t)(H_ * (NOPE_ + VDIM_)) + h * (NOPE_ + VDIM_) + c);
    }
    for (int u = tid; u < TK * (VDIM_ / 4); u += 256) {
      const int r = u / (VDIM_ / 4), c = (u % (VDIM_ / 4)) * 4;
      *(float4*)&Vs[r][c] = *(const float4*)(
          kv_up + (tok0 + k0 + r) * (size_t)(H_ * (NOPE_ + VDIM_)) + h * (NOPE_ + VDIM_) + NOPE_ + c);
    }
    for (int u = tid; u < TK * (ROPE_ / 4); u += 256) {
      const int r = u / (ROPE_ / 4), c = (u % (ROPE_ / 4)) * 4;
      *(float4*)&Kr[r][c] = *(const float4*)(k_rope + (tok0 + k0 + r) * (size_t)ROPE_ + c);
    }
    __syncthreads();

    // Scores (512 of them, 2 per thread)
    for (int sidx = tid; sidx < TQ * TK; sidx += 256) {
      const int r = sidx / TK, kk = sidx % TK;
      float s;
      if (k0 + kk > q0 + r) {
        s = -3.0e38f;  // masked
      } else {
        float acc = 0.f;
#pragma unroll
        for (int d = 0; d < NOPE_; d += 4) {
          float4 qa = *(const float4*)&Qn[r][d];
          float4 ka = *(const float4*)&Kn[kk][d];
          acc = fmaf(qa.x, ka.x, acc);
          acc = fmaf(qa.y, ka.y, acc);
          acc = fmaf(qa.z, ka.z, acc);
          acc = fmaf(qa.w, ka.w, acc);
        }
#pragma unroll
        for (int d = 0; d < ROPE_; d += 4) {
          float4 qa = *(const float4*)&Qp[r][d];
          float4 ka = *(const float4*)&Kr[kk][d];
          acc = fmaf(qa.x, ka.x, acc);
          acc = fmaf(qa.y, ka.y, acc);
          acc = fmaf(qa.z, ka.z, acc);
          acc = fmaf(qa.w, ka.w, acc);
        }
        s = acc * scale;
      }
      Ps[r][kk] = s;
    }
    __syncthreads();

    // Online-softmax stats, one thread per query row
    if (tid < TQ) {
      const int r = tid;
      float mt = -3.0e38f;
      for (int kk = 0; kk < TK; ++kk) mt = fmaxf(mt, Ps[r][kk]);
      const float m_old = row_m[r];
      const float m_new = fmaxf(m_old, mt);
      const float alpha = expf(m_old - m_new);  // 0 on first tile, 1 on fully-masked tiles
      float sum = 0.f;
      for (int kk = 0; kk < TK; ++kk) {
        const float p = expf(Ps[r][kk] - m_new);  // masked -> exp(-huge) = 0
        Ps[r][kk] = p;
        sum += p;
      }
      row_a[r] = alpha;
      row_m[r] = m_new;
      row_l[r] = row_l[r] * alpha + sum;
    }
    __syncthreads();

    // Rescale + accumulate P·V
    const float alpha = row_a[orow];
#pragma unroll
    for (int j = 0; j < 16; ++j) o[j] *= alpha;
    for (int kk = 0; kk < TK; ++kk) {
      const float p = Ps[orow][kk];
#pragma unroll
      for (int j = 0; j < 16; j += 4) {
        float4 v = *(const float4*)&Vs[kk][oc0 + j];
        o[j]     = fmaf(p, v.x, o[j]);
        o[j + 1] = fmaf(p, v.y, o[j + 1]);
        o[j + 2] = fmaf(p, v.z, o[j + 2]);
        o[j + 3] = fmaf(p, v.w, o[j + 3]);
      }
    }
  }

  const float invl = 1.f / row_l[orow];
  float* dst = attn_o + (tok0 + q0 + orow) * (size_t)(H_ * VDIM_) + h * VDIM_ + oc0;
#pragma unroll
  for (int j = 0; j < 16; j += 4) {
    float4 v;
    v.x = o[j] * invl; v.y = o[j + 1] * invl; v.z = o[j + 2] * invl; v.w = o[j + 3] * invl;
    *(float4*)&dst[j] = v;
  }
}

// ---------------------------------------------------------------------------
// Launch
// ---------------------------------------------------------------------------
extern "C" void kernel_launch(void* const* d_in, const int* in_sizes, int n_in,
                              void* d_out, int out_size, void* d_ws, size_t ws_size,
                              hipStream_t stream) {
  (void)in_sizes; (void)n_in;
  const float* x         = (const float*)d_in[0];
  const float* wq_down   = (const float*)d_in[1];
  const float* q_norm_w  = (const float*)d_in[2];
  const float* wq_up     = (const float*)d_in[3];
  const float* wq_rope   = (const float*)d_in[4];
  const float* wkv_down  = (const float*)d_in[5];
  const float* kv_norm_w = (const float*)d_in[6];
  const float* wkv_up    = (const float*)d_in[7];
  const float* wk_rope   = (const float*)d_in[8];
  const float* wo        = (const float*)d_in[9];
  float* out = (float*)d_out;

  // Workspace need (fp32 elements): 145 MB peak with aliasing below.
  const size_t NEED_ELEMS =
      (size_t)TOK_ * H_ * VDIM_ +            // attn_o (q_c/kv_c alias inside)
      (size_t)TOK_ * ROPE_ +                 // k_rope
      (size_t)TOK_ * H_ * NOPE_ +            // q_nope
      (size_t)TOK_ * H_ * ROPE_ +            // q_pe
      (size_t)TOK_ * H_ * (NOPE_ + VDIM_);   // kv_up
  if (ws_size < NEED_ELEMS * sizeof(float)) {
    // DIAGNOSTIC GUARD: never write OOB into d_ws (an OOB write would fault
    // and kill the container). Produce a deterministic wrong-but-alive
    // result instead, so the bench reports "incorrect" rather than crashing.
    hipMemsetAsync(d_out, 0, (size_t)out_size * sizeof(float), stream);
    return;
  }

  // Workspace layout. q_c (16 MB) and kv_c (8 MB) are dead before flash_attn
  // writes attn_o, so they alias the attn_o region (32 MB).
  float* ws = (float*)d_ws;
  float* attn_o = ws; ws += (size_t)TOK_ * H_ * VDIM_;           // 32 MB
  float* k_rope = ws; ws += (size_t)TOK_ * ROPE_;                //  1 MB
  float* q_nope = ws; ws += (size_t)TOK_ * H_ * NOPE_;           // 32 MB
  float* q_pe   = ws; ws += (size_t)TOK_ * H_ * ROPE_;           // 16 MB
  float* kv_up  = ws; ws += (size_t)TOK_ * H_ * (NOPE_ + VDIM_); // 64 MB
  float* q_c    = attn_o;                                        // aliases attn_o[0:16MB]
  float* kv_c   = attn_o + (size_t)TOK_ * QR_;                   // aliases attn_o[16:24MB]

  const dim3 blk(256);

  // Down projections from x
  gemm_bt<<<dim3(QR_ / BN, TOK_ / BM), blk, 0, stream>>>(x, wq_down, q_c, TOK_, QR_, DIM_);
  gemm_bt<<<dim3(KVR_ / BN, TOK_ / BM), blk, 0, stream>>>(x, wkv_down, kv_c, TOK_, KVR_, DIM_);
  gemm_bt<<<dim3(ROPE_ / BN, TOK_ / BM), blk, 0, stream>>>(x, wk_rope, k_rope, TOK_, ROPE_, DIM_);

  // RMSNorms (in place)
  rmsnorm_inplace<<<TOK_, blk, 0, stream>>>(q_c, q_norm_w, QR_);
  rmsnorm_inplace<<<TOK_, blk, 0, stream>>>(kv_c, kv_norm_w, KVR_);

  // Up projections
  gemm_bt<<<dim3(H_ * NOPE_ / BN, TOK_ / BM), blk, 0, stream>>>(q_c, wq_up, q_nope, TOK_, H_ * NOPE_, QR_);
  gemm_bt<<<dim3(H_ * ROPE_ / BN, TOK_ / BM), blk, 0, stream>>>(q_c, wq_rope, q_pe, TOK_, H_ * ROPE_, QR_);
  gemm_bt<<<dim3(H_ * (NOPE_ + VDIM_) / BN, TOK_ / BM), blk, 0, stream>>>(kv_c, wkv_up, kv_up, TOK_,
                                                                          H_ * (NOPE_ + VDIM_), KVR_);

  // RoPE (in place): q_pe has 16 heads, k_rope has 1
  {
    const int pairs_q = TOK_ * H_ * 32;
    rope_inplace<<<(pairs_q + 255) / 256, blk, 0, stream>>>(q_pe, H_, pairs_q);
    const int pairs_k = TOK_ * 32;
    rope_inplace<<<(pairs_k + 255) / 256, blk, 0, stream>>>(k_rope, 1, pairs_k);
  }

  // Attention (q_c/kv_c region is dead by now; attn_o overwritten fully)
  flash_attn<<<dim3(S_ / TQ, H_, B_), blk, 0, stream>>>(q_nope, q_pe, kv_up, k_rope, attn_o);

  // Output projection
  gemm_bt<<<dim3(DIM_ / BN, TOK_ / BM), blk, 0, stream>>>(attn_o, wo, out, TOK_, DIM_, H_ * VDIM_);
}

// Round 4
// 3363.242 us; speedup vs baseline: 1.4848x; 1.4848x over previous
//
#include <hip/hip_runtime.h>
#include <hip/hip_bf16.h>
#include <math.h>

// Problem constants (from reference)
#define B_    2
#define S_    2048
#define DIM_  2048
#define H_    16
#define NOPE_ 128
#define ROPE_ 64
#define VDIM_ 128
#define QR_   1024
#define KVR_  512
#define TOK_  (B_ * S_)   // 4096 token rows

typedef __attribute__((ext_vector_type(8))) short short8;   // 8 bf16 (4 VGPRs)
typedef __attribute__((ext_vector_type(4))) float f32x4;    // MFMA acc

// fp32 -> bf16 (round-to-nearest-even), raw ushort
__device__ __forceinline__ unsigned short f2bf(float f) {
  union { float f; unsigned u; } v; v.f = f;
  unsigned r = v.u + 0x7fffu + ((v.u >> 16) & 1u);
  return (unsigned short)(r >> 16);
}
__device__ __forceinline__ unsigned pk2(float lo, float hi) {
  return (unsigned)f2bf(lo) | ((unsigned)f2bf(hi) << 16);
}

// ---------------------------------------------------------------------------
// MFMA GEMM: C[M x N] = A[M x K] @ B[N x K]^T, fp32 in/out, bf16 MFMA compute.
// fp32 global -> cvt bf16 -> LDS staging (no extra workspace needed).
// 128x128 tile, BK=32, 256 threads = 4 waves, each wave 64x64 via 4x4 MFMAs
// of 16x16x32. LDS row stride padded to 40 bf16 (80 B) -> 2-way conflicts max.
// M, N multiples of 128; K multiple of 32.
// ---------------------------------------------------------------------------
#define LDK 40   // padded LDS row stride in bf16 elements

__global__ __launch_bounds__(256) void mfma_gemm_bt(const float* __restrict__ A,
                                                    const float* __restrict__ Bm,
                                                    float* __restrict__ C,
                                                    int M, int N, int K) {
  __shared__ unsigned short As[128 * LDK];
  __shared__ unsigned short Bs[128 * LDK];
  const int tid  = threadIdx.x;
  const int wave = tid >> 6;
  const int lane = tid & 63;
  const int quad = lane >> 4;
  const int l15  = lane & 15;
  const int m0 = blockIdx.y * 128;
  const int n0 = blockIdx.x * 128;
  const int wm = (wave & 1) * 64;
  const int wn = (wave >> 1) * 64;

  // staging mapping: thread t covers row r = t>>1, 16 cols at (t&1)*16
  const int sr = tid >> 1;
  const int sc = (tid & 1) * 16;

  f32x4 acc[4][4];
#pragma unroll
  for (int i = 0; i < 4; ++i)
#pragma unroll
    for (int j = 0; j < 4; ++j) {
      f32x4 z = {0.f, 0.f, 0.f, 0.f};
      acc[i][j] = z;
    }

  for (int k0 = 0; k0 < K; k0 += 32) {
    __syncthreads();  // previous iteration's frag reads done before overwrite
    {
      const float* pa = A + (size_t)(m0 + sr) * K + k0 + sc;
      float4 a0 = *(const float4*)(pa + 0);
      float4 a1 = *(const float4*)(pa + 4);
      float4 a2 = *(const float4*)(pa + 8);
      float4 a3 = *(const float4*)(pa + 12);
      uint4 w0, w1;
      w0.x = pk2(a0.x, a0.y); w0.y = pk2(a0.z, a0.w);
      w0.z = pk2(a1.x, a1.y); w0.w = pk2(a1.z, a1.w);
      w1.x = pk2(a2.x, a2.y); w1.y = pk2(a2.z, a2.w);
      w1.z = pk2(a3.x, a3.y); w1.w = pk2(a3.z, a3.w);
      *(uint4*)&As[sr * LDK + sc] = w0;
      *(uint4*)&As[sr * LDK + sc + 8] = w1;

      const float* pb = Bm + (size_t)(n0 + sr) * K + k0 + sc;
      float4 b0 = *(const float4*)(pb + 0);
      float4 b1 = *(const float4*)(pb + 4);
      float4 b2 = *(const float4*)(pb + 8);
      float4 b3 = *(const float4*)(pb + 12);
      uint4 v0, v1;
      v0.x = pk2(b0.x, b0.y); v0.y = pk2(b0.z, b0.w);
      v0.z = pk2(b1.x, b1.y); v0.w = pk2(b1.z, b1.w);
      v1.x = pk2(b2.x, b2.y); v1.y = pk2(b2.z, b2.w);
      v1.z = pk2(b3.x, b3.y); v1.w = pk2(b3.z, b3.w);
      *(uint4*)&Bs[sr * LDK + sc] = v0;
      *(uint4*)&Bs[sr * LDK + sc + 8] = v1;
    }
    __syncthreads();

    short8 a[4], b[4];
#pragma unroll
    for (int i = 0; i < 4; ++i)
      a[i] = *(const short8*)&As[(wm + i * 16 + l15) * LDK + quad * 8];
#pragma unroll
    for (int j = 0; j < 4; ++j)
      b[j] = *(const short8*)&Bs[(wn + j * 16 + l15) * LDK + quad * 8];
#pragma unroll
    for (int i = 0; i < 4; ++i)
#pragma unroll
      for (int j = 0; j < 4; ++j)
        acc[i][j] = __builtin_amdgcn_mfma_f32_16x16x32_bf16(a[i], b[j], acc[i][j], 0, 0, 0);
  }

  // Epilogue: C/D layout col=lane&15, row=quad*4+reg (m89-verified mapping)
#pragma unroll
  for (int i = 0; i < 4; ++i) {
#pragma unroll
    for (int j = 0; j < 4; ++j) {
#pragma unroll
      for (int r = 0; r < 4; ++r) {
        const int row = m0 + wm + i * 16 + quad * 4 + r;
        const int col = n0 + wn + j * 16 + l15;
        C[(size_t)row * N + col] = acc[i][j][r];
      }
    }
  }
}

// ---------------------------------------------------------------------------
// fp32 GEMM (kept for the small k_rope projection, N=64):
// C[M x N] = A[M x K] @ B[N x K]^T. 64x64 tile, BK=32.
// ---------------------------------------------------------------------------
#define BM 64
#define BN 64
#define BK 32

__global__ __launch_bounds__(256) void gemm_bt(const float* __restrict__ A,
                                               const float* __restrict__ Bm,
                                               float* __restrict__ C,
                                               int M, int N, int K) {
  __shared__ float As[BM][BK + 1];
  __shared__ float Bs[BN][BK + 1];
  const int tid = threadIdx.x;
  const int m0 = blockIdx.y * BM;
  const int n0 = blockIdx.x * BN;
  const int tx = tid & 15;
  const int ty = tid >> 4;
  const int lr = tid >> 3;
  const int lc = (tid & 7) << 2;
  float acc[4][4] = {};

  for (int k0 = 0; k0 < K; k0 += BK) {
#pragma unroll
    for (int i = 0; i < 2; ++i) {
      const int r = lr + i * 32;
      float4 va = *(const float4*)(A + (size_t)(m0 + r) * K + k0 + lc);
      As[r][lc] = va.x; As[r][lc + 1] = va.y; As[r][lc + 2] = va.z; As[r][lc + 3] = va.w;
      float4 vb = *(const float4*)(Bm + (size_t)(n0 + r) * K + k0 + lc);
      Bs[r][lc] = vb.x; Bs[r][lc + 1] = vb.y; Bs[r][lc + 2] = vb.z; Bs[r][lc + 3] = vb.w;
    }
    __syncthreads();
#pragma unroll
    for (int kk = 0; kk < BK; ++kk) {
      float a[4], b[4];
#pragma unroll
      for (int i = 0; i < 4; ++i) a[i] = As[ty * 4 + i][kk];
#pragma unroll
      for (int j = 0; j < 4; ++j) b[j] = Bs[tx * 4 + j][kk];
#pragma unroll
      for (int i = 0; i < 4; ++i)
#pragma unroll
        for (int j = 0; j < 4; ++j) acc[i][j] = fmaf(a[i], b[j], acc[i][j]);
    }
    __syncthreads();
  }
#pragma unroll
  for (int i = 0; i < 4; ++i)
#pragma unroll
    for (int j = 0; j < 4; ++j)
      C[(size_t)(m0 + ty * 4 + i) * N + n0 + tx * 4 + j] = acc[i][j];
}

// ---------------------------------------------------------------------------
// RMSNorm in place over rows of length n (fp32)
// ---------------------------------------------------------------------------
__global__ __launch_bounds__(256) void rmsnorm_inplace(float* __restrict__ x,
                                                       const float* __restrict__ w,
                                                       int n) {
  __shared__ float red[256];
  const int row = blockIdx.x;
  float* p = x + (size_t)row * n;
  float s = 0.f;
  for (int i = threadIdx.x; i < n; i += 256) { float v = p[i]; s += v * v; }
  red[threadIdx.x] = s;
  __syncthreads();
  for (int off = 128; off > 0; off >>= 1) {
    if (threadIdx.x < off) red[threadIdx.x] += red[threadIdx.x + off];
    __syncthreads();
  }
  const float inv = rsqrtf(red[0] / (float)n + 1e-6f);
  for (int i = threadIdx.x; i < n; i += 256) p[i] = p[i] * inv * w[i];
}

// ---------------------------------------------------------------------------
// Interleaved RoPE in place. Layout: (rows, heads*64); pos = row % S.
// ---------------------------------------------------------------------------
__global__ void rope_inplace(float* __restrict__ x, int heads, int total_pairs) {
  int idx = blockIdx.x * blockDim.x + threadIdx.x;
  if (idx >= total_pairs) return;
  const int i = idx & 31;
  const int h = (idx >> 5) % heads;
  const int row = idx / (32 * heads);
  const int pos = row & (S_ - 1);
  const float freq = expf(-9.210340371976184f * (float)i / 32.0f);
  const float ang = (float)pos * freq;
  const float c = cosf(ang), sn = sinf(ang);
  float* p = x + ((size_t)row * heads + h) * 64 + 2 * i;
  const float x1 = p[0], x2 = p[1];
  p[0] = x1 * c - x2 * sn;
  p[1] = x1 * sn + x2 * c;
}

// ---------------------------------------------------------------------------
// Flash attention (causal, online softmax), fp32 — unchanged this round.
// ---------------------------------------------------------------------------
#define TQ 32
#define TK 16

__global__ __launch_bounds__(256) void flash_attn(const float* __restrict__ q_nope,
                                                  const float* __restrict__ q_pe,
                                                  const float* __restrict__ kv_up,
                                                  const float* __restrict__ k_rope,
                                                  float* __restrict__ attn_o) {
  __shared__ float Qn[TQ][NOPE_ + 4];
  __shared__ float Qp[TQ][ROPE_ + 4];
  __shared__ float Kn[TK][NOPE_ + 4];
  __shared__ float Kr[TK][ROPE_ + 4];
  __shared__ float Vs[TK][VDIM_ + 4];
  __shared__ float Ps[TQ][TK];
  __shared__ float row_m[TQ], row_l[TQ], row_a[TQ];

  const int tid = threadIdx.x;
  const int q0 = blockIdx.x * TQ;
  const int h = blockIdx.y;
  const int b = blockIdx.z;
  const size_t tok0 = (size_t)b * S_;

  for (int u = tid; u < TQ * (NOPE_ / 4); u += 256) {
    const int r = u / (NOPE_ / 4), c = (u % (NOPE_ / 4)) * 4;
    *(float4*)&Qn[r][c] =
        *(const float4*)(q_nope + (tok0 + q0 + r) * (size_t)(H_ * NOPE_) + h * NOPE_ + c);
  }
  for (int u = tid; u < TQ * (ROPE_ / 4); u += 256) {
    const int r = u / (ROPE_ / 4), c = (u % (ROPE_ / 4)) * 4;
    *(float4*)&Qp[r][c] =
        *(const float4*)(q_pe + (tok0 + q0 + r) * (size_t)(H_ * ROPE_) + h * ROPE_ + c);
  }
  if (tid < TQ) { row_m[tid] = -3.0e38f; row_l[tid] = 0.f; }

  const int orow = tid >> 3;
  const int oc0 = (tid & 7) << 4;
  float o[16];
#pragma unroll
  for (int j = 0; j < 16; ++j) o[j] = 0.f;

  const float scale = 0.07216878364870323f;  // 1/sqrt(192)
  const int ktmax = (q0 + TQ - 1) / TK;

  for (int kt = 0; kt <= ktmax; ++kt) {
    const int k0 = kt * TK;
    __syncthreads();
    for (int u = tid; u < TK * (NOPE_ / 4); u += 256) {
      const int r = u / (NOPE_ / 4), c = (u % (NOPE_ / 4)) * 4;
      *(float4*)&Kn[r][c] = *(const float4*)(
          kv_up + (tok0 + k0 + r) * (size_t)(H_ * (NOPE_ + VDIM_)) + h * (NOPE_ + VDIM_) + c);
    }
    for (int u = tid; u < TK * (VDIM_ / 4); u += 256) {
      const int r = u / (VDIM_ / 4), c = (u % (VDIM_ / 4)) * 4;
      *(float4*)&Vs[r][c] = *(const float4*)(
          kv_up + (tok0 + k0 + r) * (size_t)(H_ * (NOPE_ + VDIM_)) + h * (NOPE_ + VDIM_) + NOPE_ + c);
    }
    for (int u = tid; u < TK * (ROPE_ / 4); u += 256) {
      const int r = u / (ROPE_ / 4), c = (u % (ROPE_ / 4)) * 4;
      *(float4*)&Kr[r][c] = *(const float4*)(k_rope + (tok0 + k0 + r) * (size_t)ROPE_ + c);
    }
    __syncthreads();

    for (int sidx = tid; sidx < TQ * TK; sidx += 256) {
      const int r = sidx / TK, kk = sidx % TK;
      float s;
      if (k0 + kk > q0 + r) {
        s = -3.0e38f;
      } else {
        float acc = 0.f;
#pragma unroll
        for (int d = 0; d < NOPE_; d += 4) {
          float4 qa = *(const float4*)&Qn[r][d];
          float4 ka = *(const float4*)&Kn[kk][d];
          acc = fmaf(qa.x, ka.x, acc);
          acc = fmaf(qa.y, ka.y, acc);
          acc = fmaf(qa.z, ka.z, acc);
          acc = fmaf(qa.w, ka.w, acc);
        }
#pragma unroll
        for (int d = 0; d < ROPE_; d += 4) {
          float4 qa = *(const float4*)&Qp[r][d];
          float4 ka = *(const float4*)&Kr[kk][d];
          acc = fmaf(qa.x, ka.x, acc);
          acc = fmaf(qa.y, ka.y, acc);
          acc = fmaf(qa.z, ka.z, acc);
          acc = fmaf(qa.w, ka.w, acc);
        }
        s = acc * scale;
      }
      Ps[r][kk] = s;
    }
    __syncthreads();

    if (tid < TQ) {
      const int r = tid;
      float mt = -3.0e38f;
      for (int kk = 0; kk < TK; ++kk) mt = fmaxf(mt, Ps[r][kk]);
      const float m_old = row_m[r];
      const float m_new = fmaxf(m_old, mt);
      const float alpha = expf(m_old - m_new);
      float sum = 0.f;
      for (int kk = 0; kk < TK; ++kk) {
        const float p = expf(Ps[r][kk] - m_new);
        Ps[r][kk] = p;
        sum += p;
      }
      row_a[r] = alpha;
      row_m[r] = m_new;
      row_l[r] = row_l[r] * alpha + sum;
    }
    __syncthreads();

    const float alpha = row_a[orow];
#pragma unroll
    for (int j = 0; j < 16; ++j) o[j] *= alpha;
    for (int kk = 0; kk < TK; ++kk) {
      const float p = Ps[orow][kk];
#pragma unroll
      for (int j = 0; j < 16; j += 4) {
        float4 v = *(const float4*)&Vs[kk][oc0 + j];
        o[j]     = fmaf(p, v.x, o[j]);
        o[j + 1] = fmaf(p, v.y, o[j + 1]);
        o[j + 2] = fmaf(p, v.z, o[j + 2]);
        o[j + 3] = fmaf(p, v.w, o[j + 3]);
      }
    }
  }

  const float invl = 1.f / row_l[orow];
  float* dst = attn_o + (tok0 + q0 + orow) * (size_t)(H_ * VDIM_) + h * VDIM_ + oc0;
#pragma unroll
  for (int j = 0; j < 16; j += 4) {
    float4 v;
    v.x = o[j] * invl; v.y = o[j + 1] * invl; v.z = o[j + 2] * invl; v.w = o[j + 3] * invl;
    *(float4*)&dst[j] = v;
  }
}

// ---------------------------------------------------------------------------
// Launch
// ---------------------------------------------------------------------------
extern "C" void kernel_launch(void* const* d_in, const int* in_sizes, int n_in,
                              void* d_out, int out_size, void* d_ws, size_t ws_size,
                              hipStream_t stream) {
  (void)in_sizes; (void)n_in;
  const float* x         = (const float*)d_in[0];
  const float* wq_down   = (const float*)d_in[1];
  const float* q_norm_w  = (const float*)d_in[2];
  const float* wq_up     = (const float*)d_in[3];
  const float* wq_rope   = (const float*)d_in[4];
  const float* wkv_down  = (const float*)d_in[5];
  const float* kv_norm_w = (const float*)d_in[6];
  const float* wkv_up    = (const float*)d_in[7];
  const float* wk_rope   = (const float*)d_in[8];
  const float* wo        = (const float*)d_in[9];
  float* out = (float*)d_out;

  // Workspace need (unchanged from R3's passing run): 145 MB peak.
  const size_t NEED_ELEMS =
      (size_t)TOK_ * H_ * VDIM_ +            // attn_o (q_c/kv_c alias inside)
      (size_t)TOK_ * ROPE_ +                 // k_rope
      (size_t)TOK_ * H_ * NOPE_ +            // q_nope
      (size_t)TOK_ * H_ * ROPE_ +            // q_pe
      (size_t)TOK_ * H_ * (NOPE_ + VDIM_);   // kv_up
  if (ws_size < NEED_ELEMS * sizeof(float)) {
    hipMemsetAsync(d_out, 0, (size_t)out_size * sizeof(float), stream);
    return;
  }

  float* ws = (float*)d_ws;
  float* attn_o = ws; ws += (size_t)TOK_ * H_ * VDIM_;           // 32 MB
  float* k_rope = ws; ws += (size_t)TOK_ * ROPE_;                //  1 MB
  float* q_nope = ws; ws += (size_t)TOK_ * H_ * NOPE_;           // 32 MB
  float* q_pe   = ws; ws += (size_t)TOK_ * H_ * ROPE_;           // 16 MB
  float* kv_up  = ws; ws += (size_t)TOK_ * H_ * (NOPE_ + VDIM_); // 64 MB
  float* q_c    = attn_o;                                        // aliases attn_o[0:16MB]
  float* kv_c   = attn_o + (size_t)TOK_ * QR_;                   // aliases attn_o[16:24MB]

  const dim3 blk(256);

  // Down projections from x (bf16 MFMA; k_rope small -> fp32 path)
  mfma_gemm_bt<<<dim3(QR_ / 128, TOK_ / 128), blk, 0, stream>>>(x, wq_down, q_c, TOK_, QR_, DIM_);
  mfma_gemm_bt<<<dim3(KVR_ / 128, TOK_ / 128), blk, 0, stream>>>(x, wkv_down, kv_c, TOK_, KVR_, DIM_);
  gemm_bt<<<dim3(ROPE_ / BN, TOK_ / BM), blk, 0, stream>>>(x, wk_rope, k_rope, TOK_, ROPE_, DIM_);

  // RMSNorms (in place, fp32)
  rmsnorm_inplace<<<TOK_, blk, 0, stream>>>(q_c, q_norm_w, QR_);
  rmsnorm_inplace<<<TOK_, blk, 0, stream>>>(kv_c, kv_norm_w, KVR_);

  // Up projections (bf16 MFMA)
  mfma_gemm_bt<<<dim3(H_ * NOPE_ / 128, TOK_ / 128), blk, 0, stream>>>(q_c, wq_up, q_nope, TOK_, H_ * NOPE_, QR_);
  mfma_gemm_bt<<<dim3(H_ * ROPE_ / 128, TOK_ / 128), blk, 0, stream>>>(q_c, wq_rope, q_pe, TOK_, H_ * ROPE_, QR_);
  mfma_gemm_bt<<<dim3(H_ * (NOPE_ + VDIM_) / 128, TOK_ / 128), blk, 0, stream>>>(kv_c, wkv_up, kv_up, TOK_,
                                                                                 H_ * (NOPE_ + VDIM_), KVR_);

  // RoPE (in place, fp32)
  {
    const int pairs_q = TOK_ * H_ * 32;
    rope_inplace<<<(pairs_q + 255) / 256, blk, 0, stream>>>(q_pe, H_, pairs_q);
    const int pairs_k = TOK_ * 32;
    rope_inplace<<<(pairs_k + 255) / 256, blk, 0, stream>>>(k_rope, 1, pairs_k);
  }

  // Attention (unchanged)
  flash_attn<<<dim3(S_ / TQ, H_, B_), blk, 0, stream>>>(q_nope, q_pe, kv_up, k_rope, attn_o);

  // Output projection (bf16 MFMA)
  mfma_gemm_bt<<<dim3(DIM_ / 128, TOK_ / 128), blk, 0, stream>>>(attn_o, wo, out, TOK_, DIM_, H_ * VDIM_);
}

// Round 5
// 1101.036 us; speedup vs baseline: 4.5354x; 3.0546x over previous
//
#include <hip/hip_runtime.h>
#include <hip/hip_bf16.h>
#include <math.h>

// Problem constants (from reference)
#define B_    2
#define S_    2048
#define DIM_  2048
#define H_    16
#define NOPE_ 128
#define ROPE_ 64
#define VDIM_ 128
#define QR_   1024
#define KVR_  512
#define TOK_  (B_ * S_)   // 4096 token rows

typedef __attribute__((ext_vector_type(8))) short short8;   // 8 bf16 (4 VGPRs)
typedef __attribute__((ext_vector_type(4))) float f32x4;    // MFMA acc

// fp32 -> bf16 (round-to-nearest-even), raw ushort
__device__ __forceinline__ unsigned short f2bf(float f) {
  union { float f; unsigned u; } v; v.f = f;
  unsigned r = v.u + 0x7fffu + ((v.u >> 16) & 1u);
  return (unsigned short)(r >> 16);
}
__device__ __forceinline__ unsigned pk2(float lo, float hi) {
  return (unsigned)f2bf(lo) | ((unsigned)f2bf(hi) << 16);
}
__device__ __forceinline__ short8 pack8(float4 f0, float4 f1) {
  union { short8 s; uint4 u; } t;
  t.u.x = pk2(f0.x, f0.y); t.u.y = pk2(f0.z, f0.w);
  t.u.z = pk2(f1.x, f1.y); t.u.w = pk2(f1.z, f1.w);
  return t.s;
}

// ---------------------------------------------------------------------------
// MFMA GEMM: C[M x N] = A[M x K] @ B[N x K]^T, fp32 in/out, bf16 MFMA compute.
// 128x128 tile, BK=32, 256 threads = 4 waves, each wave 64x64 via 4x4 MFMAs.
// ---------------------------------------------------------------------------
#define LDK 40   // padded LDS row stride in bf16 elements

__global__ __launch_bounds__(256) void mfma_gemm_bt(const float* __restrict__ A,
                                                    const float* __restrict__ Bm,
                                                    float* __restrict__ C,
                                                    int M, int N, int K) {
  __shared__ unsigned short As[128 * LDK];
  __shared__ unsigned short Bs[128 * LDK];
  const int tid  = threadIdx.x;
  const int wave = tid >> 6;
  const int lane = tid & 63;
  const int quad = lane >> 4;
  const int l15  = lane & 15;
  const int m0 = blockIdx.y * 128;
  const int n0 = blockIdx.x * 128;
  const int wm = (wave & 1) * 64;
  const int wn = (wave >> 1) * 64;

  const int sr = tid >> 1;
  const int sc = (tid & 1) * 16;

  f32x4 acc[4][4];
#pragma unroll
  for (int i = 0; i < 4; ++i)
#pragma unroll
    for (int j = 0; j < 4; ++j) {
      f32x4 z = {0.f, 0.f, 0.f, 0.f};
      acc[i][j] = z;
    }

  for (int k0 = 0; k0 < K; k0 += 32) {
    __syncthreads();
    {
      const float* pa = A + (size_t)(m0 + sr) * K + k0 + sc;
      float4 a0 = *(const float4*)(pa + 0);
      float4 a1 = *(const float4*)(pa + 4);
      float4 a2 = *(const float4*)(pa + 8);
      float4 a3 = *(const float4*)(pa + 12);
      uint4 w0, w1;
      w0.x = pk2(a0.x, a0.y); w0.y = pk2(a0.z, a0.w);
      w0.z = pk2(a1.x, a1.y); w0.w = pk2(a1.z, a1.w);
      w1.x = pk2(a2.x, a2.y); w1.y = pk2(a2.z, a2.w);
      w1.z = pk2(a3.x, a3.y); w1.w = pk2(a3.z, a3.w);
      *(uint4*)&As[sr * LDK + sc] = w0;
      *(uint4*)&As[sr * LDK + sc + 8] = w1;

      const float* pb = Bm + (size_t)(n0 + sr) * K + k0 + sc;
      float4 b0 = *(const float4*)(pb + 0);
      float4 b1 = *(const float4*)(pb + 4);
      float4 b2 = *(const float4*)(pb + 8);
      float4 b3 = *(const float4*)(pb + 12);
      uint4 v0, v1;
      v0.x = pk2(b0.x, b0.y); v0.y = pk2(b0.z, b0.w);
      v0.z = pk2(b1.x, b1.y); v0.w = pk2(b1.z, b1.w);
      v1.x = pk2(b2.x, b2.y); v1.y = pk2(b2.z, b2.w);
      v1.z = pk2(b3.x, b3.y); v1.w = pk2(b3.z, b3.w);
      *(uint4*)&Bs[sr * LDK + sc] = v0;
      *(uint4*)&Bs[sr * LDK + sc + 8] = v1;
    }
    __syncthreads();

    short8 a[4], b[4];
#pragma unroll
    for (int i = 0; i < 4; ++i)
      a[i] = *(const short8*)&As[(wm + i * 16 + l15) * LDK + quad * 8];
#pragma unroll
    for (int j = 0; j < 4; ++j)
      b[j] = *(const short8*)&Bs[(wn + j * 16 + l15) * LDK + quad * 8];
#pragma unroll
    for (int i = 0; i < 4; ++i)
#pragma unroll
      for (int j = 0; j < 4; ++j)
        acc[i][j] = __builtin_amdgcn_mfma_f32_16x16x32_bf16(a[i], b[j], acc[i][j], 0, 0, 0);
  }

#pragma unroll
  for (int i = 0; i < 4; ++i) {
#pragma unroll
    for (int j = 0; j < 4; ++j) {
#pragma unroll
      for (int r = 0; r < 4; ++r) {
        const int row = m0 + wm + i * 16 + quad * 4 + r;
        const int col = n0 + wn + j * 16 + l15;
        C[(size_t)row * N + col] = acc[i][j][r];
      }
    }
  }
}

// ---------------------------------------------------------------------------
// fp32 GEMM (kept for the small k_rope projection, N=64)
// ---------------------------------------------------------------------------
#define BM 64
#define BN 64
#define BK 32

__global__ __launch_bounds__(256) void gemm_bt(const float* __restrict__ A,
                                               const float* __restrict__ Bm,
                                               float* __restrict__ C,
                                               int M, int N, int K) {
  __shared__ float As[BM][BK + 1];
  __shared__ float Bs[BN][BK + 1];
  const int tid = threadIdx.x;
  const int m0 = blockIdx.y * BM;
  const int n0 = blockIdx.x * BN;
  const int tx = tid & 15;
  const int ty = tid >> 4;
  const int lr = tid >> 3;
  const int lc = (tid & 7) << 2;
  float acc[4][4] = {};

  for (int k0 = 0; k0 < K; k0 += BK) {
#pragma unroll
    for (int i = 0; i < 2; ++i) {
      const int r = lr + i * 32;
      float4 va = *(const float4*)(A + (size_t)(m0 + r) * K + k0 + lc);
      As[r][lc] = va.x; As[r][lc + 1] = va.y; As[r][lc + 2] = va.z; As[r][lc + 3] = va.w;
      float4 vb = *(const float4*)(Bm + (size_t)(n0 + r) * K + k0 + lc);
      Bs[r][lc] = vb.x; Bs[r][lc + 1] = vb.y; Bs[r][lc + 2] = vb.z; Bs[r][lc + 3] = vb.w;
    }
    __syncthreads();
#pragma unroll
    for (int kk = 0; kk < BK; ++kk) {
      float a[4], b[4];
#pragma unroll
      for (int i = 0; i < 4; ++i) a[i] = As[ty * 4 + i][kk];
#pragma unroll
      for (int j = 0; j < 4; ++j) b[j] = Bs[tx * 4 + j][kk];
#pragma unroll
      for (int i = 0; i < 4; ++i)
#pragma unroll
        for (int j = 0; j < 4; ++j) acc[i][j] = fmaf(a[i], b[j], acc[i][j]);
    }
    __syncthreads();
  }
#pragma unroll
  for (int i = 0; i < 4; ++i)
#pragma unroll
    for (int j = 0; j < 4; ++j)
      C[(size_t)(m0 + ty * 4 + i) * N + n0 + tx * 4 + j] = acc[i][j];
}

// ---------------------------------------------------------------------------
// RMSNorm in place over rows of length n (fp32)
// ---------------------------------------------------------------------------
__global__ __launch_bounds__(256) void rmsnorm_inplace(float* __restrict__ x,
                                                       const float* __restrict__ w,
                                                       int n) {
  __shared__ float red[256];
  const int row = blockIdx.x;
  float* p = x + (size_t)row * n;
  float s = 0.f;
  for (int i = threadIdx.x; i < n; i += 256) { float v = p[i]; s += v * v; }
  red[threadIdx.x] = s;
  __syncthreads();
  for (int off = 128; off > 0; off >>= 1) {
    if (threadIdx.x < off) red[threadIdx.x] += red[threadIdx.x + off];
    __syncthreads();
  }
  const float inv = rsqrtf(red[0] / (float)n + 1e-6f);
  for (int i = threadIdx.x; i < n; i += 256) p[i] = p[i] * inv * w[i];
}

// ---------------------------------------------------------------------------
// Interleaved RoPE in place. Layout: (rows, heads*64); pos = row % S.
// ---------------------------------------------------------------------------
__global__ void rope_inplace(float* __restrict__ x, int heads, int total_pairs) {
  int idx = blockIdx.x * blockDim.x + threadIdx.x;
  if (idx >= total_pairs) return;
  const int i = idx & 31;
  const int h = (idx >> 5) % heads;
  const int row = idx / (32 * heads);
  const int pos = row & (S_ - 1);
  const float freq = expf(-9.210340371976184f * (float)i / 32.0f);
  const float ang = (float)pos * freq;
  const float c = cosf(ang), sn = sinf(ang);
  float* p = x + ((size_t)row * heads + h) * 64 + 2 * i;
  const float x1 = p[0], x2 = p[1];
  p[0] = x1 * c - x2 * sn;
  p[1] = x1 * sn + x2 * c;
}

// ---------------------------------------------------------------------------
// MFMA flash attention (causal, online softmax). bf16 MFMA, fp32 softmax/acc.
// Block: 256 threads = 4 waves. Q-tile 64 rows; K-tiles of 64 keys.
// Wave w owns Q rows [w*16, w*16+16). Q frags live in registers (A-layout).
// K staged to LDS [64 x 192] bf16 (B-layout reads); V staged TRANSPOSED
// [128 feat x 64 key] so PV B-frags are contiguous; P transposed C->A layout
// via LDS (m120-verified). Softmax stats per row in registers + shfl_xor.
// ---------------------------------------------------------------------------
#define LK 200   // Ks stride (192 + 8 pad), bf16 elems
#define LV 72    // Vt / Ps stride (64 + 8 pad), bf16 elems

__global__ __launch_bounds__(256) void flash_attn_mfma(const float* __restrict__ q_nope,
                                                       const float* __restrict__ q_pe,
                                                       const float* __restrict__ kv_up,
                                                       const float* __restrict__ k_rope,
                                                       float* __restrict__ attn_o) {
  __shared__ unsigned short Ks[64 * LK];   // 25.6 KB: keys x 192 feats
  __shared__ unsigned short Vt[128 * LV];  // 18.4 KB: feats x 64 keys
  __shared__ unsigned short Ps[64 * LV];   //  9.2 KB: q rows x 64 keys

  const int tid  = threadIdx.x;
  const int wave = tid >> 6;
  const int lane = tid & 63;
  const int quad = lane >> 4;
  const int l15  = lane & 15;
  const int qt = blockIdx.x;
  const int q0 = qt * 64;
  const int h  = blockIdx.y;
  const int b  = blockIdx.z;
  const size_t tok0 = (size_t)b * S_;
  const int KVW = H_ * (NOPE_ + VDIM_);   // 4096
  const float scale = 0.07216878364870323f;  // 1/sqrt(192)

  // --- Q fragments: rows q0 + wave*16 + l15, 6 k-steps of 32 feats ---
  short8 qf[6];
  {
    const size_t qrow = tok0 + q0 + wave * 16 + l15;
    const float* pn = q_nope + qrow * (size_t)(H_ * NOPE_) + h * NOPE_;
    const float* pp = q_pe   + qrow * (size_t)(H_ * ROPE_) + h * ROPE_;
#pragma unroll
    for (int s = 0; s < 4; ++s) {
      float4 f0 = *(const float4*)(pn + s * 32 + quad * 8);
      float4 f1 = *(const float4*)(pn + s * 32 + quad * 8 + 4);
      qf[s] = pack8(f0, f1);
    }
#pragma unroll
    for (int s = 4; s < 6; ++s) {
      float4 f0 = *(const float4*)(pp + (s - 4) * 32 + quad * 8);
      float4 f1 = *(const float4*)(pp + (s - 4) * 32 + quad * 8 + 4);
      qf[s] = pack8(f0, f1);
    }
  }

  // Online-softmax state per owned row (row = wave*16 + quad*4 + reg)
  float m_st[4], l_st[4];
#pragma unroll
  for (int r = 0; r < 4; ++r) { m_st[r] = -1e30f; l_st[r] = 0.f; }
  f32x4 o[8];
#pragma unroll
  for (int nt = 0; nt < 8; ++nt) { f32x4 z = {0.f, 0.f, 0.f, 0.f}; o[nt] = z; }

  for (int kt = 0; kt <= qt; ++kt) {
    const int k0 = kt * 64;
    __syncthreads();  // prior tile's Ks/Vt reads complete

    // --- stage K (64 x 192) ---
#pragma unroll
    for (int i = 0; i < 3; ++i) {
      const int u = tid + i * 256;           // 768 units
      const int row = u / 12, fg = u % 12;   // fg: 16-feat group
      const size_t krow = tok0 + k0 + row;
      const float* p = (fg < 8) ? (kv_up + krow * KVW + h * 256 + fg * 16)
                                : (k_rope + krow * (size_t)ROPE_ + (fg - 8) * 16);
      float4 f0 = *(const float4*)(p + 0);
      float4 f1 = *(const float4*)(p + 4);
      float4 f2 = *(const float4*)(p + 8);
      float4 f3 = *(const float4*)(p + 12);
      uint4 w0, w1;
      w0.x = pk2(f0.x, f0.y); w0.y = pk2(f0.z, f0.w);
      w0.z = pk2(f1.x, f1.y); w0.w = pk2(f1.z, f1.w);
      w1.x = pk2(f2.x, f2.y); w1.y = pk2(f2.z, f2.w);
      w1.z = pk2(f3.x, f3.y); w1.w = pk2(f3.z, f3.w);
      *(uint4*)&Ks[row * LK + fg * 16] = w0;
      *(uint4*)&Ks[row * LK + fg * 16 + 8] = w1;
    }
    // --- stage V transposed (feat-major) ---
#pragma unroll
    for (int i = 0; i < 4; ++i) {
      const int u = tid + i * 256;           // 1024 units
      const int kp = u >> 5, fg = u & 31;    // key pair, 4-feat group
      const float* p0 = kv_up + (tok0 + k0 + 2 * kp) * (size_t)KVW + h * 256 + NOPE_ + fg * 4;
      const float* p1 = p0 + KVW;
      float4 a = *(const float4*)p0;
      float4 c = *(const float4*)p1;
      *(unsigned*)&Vt[(fg * 4 + 0) * LV + 2 * kp] = pk2(a.x, c.x);
      *(unsigned*)&Vt[(fg * 4 + 1) * LV + 2 * kp] = pk2(a.y, c.y);
      *(unsigned*)&Vt[(fg * 4 + 2) * LV + 2 * kp] = pk2(a.z, c.z);
      *(unsigned*)&Vt[(fg * 4 + 3) * LV + 2 * kp] = pk2(a.w, c.w);
    }
    __syncthreads();

    // --- S = Q K^T (wave strip: 16 x 64) ---
    f32x4 sacc[4];
#pragma unroll
    for (int nt = 0; nt < 4; ++nt) { f32x4 z = {0.f, 0.f, 0.f, 0.f}; sacc[nt] = z; }
#pragma unroll
    for (int s = 0; s < 6; ++s) {
#pragma unroll
      for (int nt = 0; nt < 4; ++nt) {
        short8 kb = *(const short8*)&Ks[(nt * 16 + l15) * LK + s * 32 + quad * 8];
        sacc[nt] = __builtin_amdgcn_mfma_f32_16x16x32_bf16(qf[s], kb, sacc[nt], 0, 0, 0);
      }
    }

    // --- mask + scale ---
    float sc[4][4];
#pragma unroll
    for (int nt = 0; nt < 4; ++nt)
#pragma unroll
      for (int r = 0; r < 4; ++r) {
        float v = sacc[nt][r] * scale;
        if (kt == qt && (nt * 16 + l15) > (wave * 16 + quad * 4 + r)) v = -1e30f;
        sc[nt][r] = v;
      }

    // --- online softmax (rows owned per-wave; reduce over l15 group) ---
    float mt[4];
#pragma unroll
    for (int r = 0; r < 4; ++r)
      mt[r] = fmaxf(fmaxf(sc[0][r], sc[1][r]), fmaxf(sc[2][r], sc[3][r]));
#pragma unroll
    for (int mask = 1; mask <= 8; mask <<= 1)
#pragma unroll
      for (int r = 0; r < 4; ++r) mt[r] = fmaxf(mt[r], __shfl_xor(mt[r], mask, 64));

    float al[4], rs[4];
#pragma unroll
    for (int r = 0; r < 4; ++r) {
      const float mn = fmaxf(m_st[r], mt[r]);
      al[r] = expf(m_st[r] - mn);
      m_st[r] = mn;
      rs[r] = 0.f;
    }
#pragma unroll
    for (int nt = 0; nt < 4; ++nt)
#pragma unroll
      for (int r = 0; r < 4; ++r) {
        const float p = expf(sc[nt][r] - m_st[r]);
        sc[nt][r] = p;
        rs[r] += p;
      }
#pragma unroll
    for (int mask = 1; mask <= 8; mask <<= 1)
#pragma unroll
      for (int r = 0; r < 4; ++r) rs[r] += __shfl_xor(rs[r], mask, 64);
#pragma unroll
    for (int r = 0; r < 4; ++r) l_st[r] = l_st[r] * al[r] + rs[r];

    // --- P: C-layout regs -> LDS (bf16) for A-layout reads ---
#pragma unroll
    for (int nt = 0; nt < 4; ++nt)
#pragma unroll
      for (int r = 0; r < 4; ++r)
        Ps[(wave * 16 + quad * 4 + r) * LV + nt * 16 + l15] = f2bf(sc[nt][r]);
    __syncthreads();  // Ps visible (cross-lane within wave; be safe)

    // --- O = O*alpha + P V ---
#pragma unroll
    for (int nt = 0; nt < 8; ++nt)
#pragma unroll
      for (int r = 0; r < 4; ++r) o[nt][r] *= al[r];
#pragma unroll
    for (int s = 0; s < 2; ++s) {
      short8 pa = *(const short8*)&Ps[(wave * 16 + l15) * LV + s * 32 + quad * 8];
#pragma unroll
      for (int nt = 0; nt < 8; ++nt) {
        short8 vb = *(const short8*)&Vt[(nt * 16 + l15) * LV + s * 32 + quad * 8];
        o[nt] = __builtin_amdgcn_mfma_f32_16x16x32_bf16(pa, vb, o[nt], 0, 0, 0);
      }
    }
  }

  // --- epilogue ---
  float invl[4];
#pragma unroll
  for (int r = 0; r < 4; ++r) invl[r] = 1.f / l_st[r];
#pragma unroll
  for (int nt = 0; nt < 8; ++nt)
#pragma unroll
    for (int r = 0; r < 4; ++r) {
      const size_t row = tok0 + q0 + wave * 16 + quad * 4 + r;
      attn_o[row * (size_t)(H_ * VDIM_) + h * VDIM_ + nt * 16 + l15] = o[nt][r] * invl[r];
    }
}

// ---------------------------------------------------------------------------
// Launch
// ---------------------------------------------------------------------------
extern "C" void kernel_launch(void* const* d_in, const int* in_sizes, int n_in,
                              void* d_out, int out_size, void* d_ws, size_t ws_size,
                              hipStream_t stream) {
  (void)in_sizes; (void)n_in;
  const float* x         = (const float*)d_in[0];
  const float* wq_down   = (const float*)d_in[1];
  const float* q_norm_w  = (const float*)d_in[2];
  const float* wq_up     = (const float*)d_in[3];
  const float* wq_rope   = (const float*)d_in[4];
  const float* wkv_down  = (const float*)d_in[5];
  const float* kv_norm_w = (const float*)d_in[6];
  const float* wkv_up    = (const float*)d_in[7];
  const float* wk_rope   = (const float*)d_in[8];
  const float* wo        = (const float*)d_in[9];
  float* out = (float*)d_out;

  const size_t NEED_ELEMS =
      (size_t)TOK_ * H_ * VDIM_ +            // attn_o (q_c/kv_c alias inside)
      (size_t)TOK_ * ROPE_ +                 // k_rope
      (size_t)TOK_ * H_ * NOPE_ +            // q_nope
      (size_t)TOK_ * H_ * ROPE_ +            // q_pe
      (size_t)TOK_ * H_ * (NOPE_ + VDIM_);   // kv_up
  if (ws_size < NEED_ELEMS * sizeof(float)) {
    hipMemsetAsync(d_out, 0, (size_t)out_size * sizeof(float), stream);
    return;
  }

  float* ws = (float*)d_ws;
  float* attn_o = ws; ws += (size_t)TOK_ * H_ * VDIM_;           // 32 MB
  float* k_rope = ws; ws += (size_t)TOK_ * ROPE_;                //  1 MB
  float* q_nope = ws; ws += (size_t)TOK_ * H_ * NOPE_;           // 32 MB
  float* q_pe   = ws; ws += (size_t)TOK_ * H_ * ROPE_;           // 16 MB
  float* kv_up  = ws; ws += (size_t)TOK_ * H_ * (NOPE_ + VDIM_); // 64 MB
  float* q_c    = attn_o;                                        // aliases attn_o[0:16MB]
  float* kv_c   = attn_o + (size_t)TOK_ * QR_;                   // aliases attn_o[16:24MB]

  const dim3 blk(256);

  // Down projections from x (bf16 MFMA; k_rope small -> fp32 path)
  mfma_gemm_bt<<<dim3(QR_ / 128, TOK_ / 128), blk, 0, stream>>>(x, wq_down, q_c, TOK_, QR_, DIM_);
  mfma_gemm_bt<<<dim3(KVR_ / 128, TOK_ / 128), blk, 0, stream>>>(x, wkv_down, kv_c, TOK_, KVR_, DIM_);
  gemm_bt<<<dim3(ROPE_ / BN, TOK_ / BM), blk, 0, stream>>>(x, wk_rope, k_rope, TOK_, ROPE_, DIM_);

  // RMSNorms (in place, fp32)
  rmsnorm_inplace<<<TOK_, blk, 0, stream>>>(q_c, q_norm_w, QR_);
  rmsnorm_inplace<<<TOK_, blk, 0, stream>>>(kv_c, kv_norm_w, KVR_);

  // Up projections (bf16 MFMA)
  mfma_gemm_bt<<<dim3(H_ * NOPE_ / 128, TOK_ / 128), blk, 0, stream>>>(q_c, wq_up, q_nope, TOK_, H_ * NOPE_, QR_);
  mfma_gemm_bt<<<dim3(H_ * ROPE_ / 128, TOK_ / 128), blk, 0, stream>>>(q_c, wq_rope, q_pe, TOK_, H_ * ROPE_, QR_);
  mfma_gemm_bt<<<dim3(H_ * (NOPE_ + VDIM_) / 128, TOK_ / 128), blk, 0, stream>>>(kv_c, wkv_up, kv_up, TOK_,
                                                                                 H_ * (NOPE_ + VDIM_), KVR_);

  // RoPE (in place, fp32)
  {
    const int pairs_q = TOK_ * H_ * 32;
    rope_inplace<<<(pairs_q + 255) / 256, blk, 0, stream>>>(q_pe, H_, pairs_q);
    const int pairs_k = TOK_ * 32;
    rope_inplace<<<(pairs_k + 255) / 256, blk, 0, stream>>>(k_rope, 1, pairs_k);
  }

  // Attention (bf16 MFMA flash)
  flash_attn_mfma<<<dim3(S_ / 64, H_, B_), blk, 0, stream>>>(q_nope, q_pe, kv_up, k_rope, attn_o);

  // Output projection (bf16 MFMA)
  mfma_gemm_bt<<<dim3(DIM_ / 128, TOK_ / 128), blk, 0, stream>>>(attn_o, wo, out, TOK_, DIM_, H_ * VDIM_);
}

// Round 6
// 786.271 us; speedup vs baseline: 6.3511x; 1.4003x over previous
//
#include <hip/hip_runtime.h>
#include <hip/hip_bf16.h>
#include <math.h>

// Problem constants (from reference)
#define B_    2
#define S_    2048
#define DIM_  2048
#define H_    16
#define NOPE_ 128
#define ROPE_ 64
#define VDIM_ 128
#define QR_   1024
#define KVR_  512
#define TOK_  (B_ * S_)   // 4096 token rows

typedef __attribute__((ext_vector_type(8))) short short8;   // 8 bf16 (4 VGPRs)
typedef __attribute__((ext_vector_type(4))) float f32x4;    // MFMA acc

// fp32 -> bf16 (round-to-nearest-even), raw ushort
__device__ __forceinline__ unsigned short f2bf(float f) {
  union { float f; unsigned u; } v; v.f = f;
  unsigned r = v.u + 0x7fffu + ((v.u >> 16) & 1u);
  return (unsigned short)(r >> 16);
}
__device__ __forceinline__ unsigned pk2(float lo, float hi) {
  return (unsigned)f2bf(lo) | ((unsigned)f2bf(hi) << 16);
}

// async global->LDS, 16 B per lane. LDS dest is wave-uniform base; HW scatters
// lane i to base + i*16 (m104/m108). Compiler drains vmcnt before s_barrier.
__device__ __forceinline__ void gl_lds16(const unsigned short* g, unsigned short* lds_base) {
  __builtin_amdgcn_global_load_lds(
      (const __attribute__((address_space(1))) void*)g,
      (__attribute__((address_space(3))) void*)lds_base,
      16, 0, 0);
}

// output store helpers (fp32 or bf16 C)
__device__ __forceinline__ void store_out(float* p, float v) { *p = v; }
__device__ __forceinline__ void store_out(unsigned short* p, float v) { *p = f2bf(v); }

// ---------------------------------------------------------------------------
// fp32 -> bf16 bulk cast. n8 = elements/8.
// ---------------------------------------------------------------------------
__global__ __launch_bounds__(256) void cvt_bf16(const float* __restrict__ in,
                                                unsigned short* __restrict__ o, int n8) {
  const int idx = blockIdx.x * 256 + threadIdx.x;
  if (idx >= n8) return;
  float4 f0 = *(const float4*)(in + (size_t)idx * 8);
  float4 f1 = *(const float4*)(in + (size_t)idx * 8 + 4);
  uint4 u;
  u.x = pk2(f0.x, f0.y); u.y = pk2(f0.z, f0.w);
  u.z = pk2(f1.x, f1.y); u.w = pk2(f1.z, f1.w);
  *(uint4*)&o[(size_t)idx * 8] = u;
}

// ---------------------------------------------------------------------------
// MFMA GEMM (m97-style): C[M x N] = A[M x K] @ B[N x K]^T.
// A,B bf16 row-major (K contiguous); C fp32 or bf16 (OutT).
// 128x128 tile, BK=32, 256 threads = 4 waves, wave does 64x64 (4x4 MFMAs).
// Staging via global_load_lds width=16 into an XOR-swizzled no-pad layout:
//   chunk (row, quad) [8 elems] lives at slot row*4 + (quad ^ ((row>>1)&3)).
// -> ds_read_b128 frag reads hit each 4-bank group exactly 2x (free, m136);
//    stores are linear 1 KB bursts (builtin requirement).
// N may be a non-multiple of 128 (multiple of 16): staging rows clamp,
// C stores guard col < N. M multiple of 128, K multiple of 32.
// ---------------------------------------------------------------------------
template <typename OutT>
__global__ __launch_bounds__(256) void gemm_bf16(const unsigned short* __restrict__ A,
                                                 const unsigned short* __restrict__ Bm,
                                                 OutT* __restrict__ C,
                                                 int M, int N, int K) {
  __shared__ unsigned short As[128 * 32];
  __shared__ unsigned short Bs[128 * 32];
  const int tid  = threadIdx.x;
  const int wave = tid >> 6;
  const int lane = tid & 63;
  const int quad = lane >> 4;
  const int l15  = lane & 15;
  const int m0 = blockIdx.y * 128;
  const int n0 = blockIdx.x * 128;
  const int wm = (wave & 1) * 64;
  const int wn = (wave >> 1) * 64;

  // this lane's two staging slots (per array): s = wave*128 + i*64 + lane
  int srow[2], sq[2];
#pragma unroll
  for (int i = 0; i < 2; ++i) {
    const int s = wave * 128 + i * 64 + lane;
    srow[i] = s >> 2;
    sq[i] = (s & 3) ^ ((srow[i] >> 1) & 3);   // content quad stored at this slot
  }

  f32x4 acc[4][4];
#pragma unroll
  for (int i = 0; i < 4; ++i)
#pragma unroll
    for (int j = 0; j < 4; ++j) {
      f32x4 z = {0.f, 0.f, 0.f, 0.f};
      acc[i][j] = z;
    }

  for (int k0 = 0; k0 < K; k0 += 32) {
    __syncthreads();  // prior frag reads done before overwrite
#pragma unroll
    for (int i = 0; i < 2; ++i) {
      const int ra = m0 + srow[i];
      const int rb = min(n0 + srow[i], N - 1);   // clamp for N<128 tiles
      gl_lds16(A + (size_t)ra * K + k0 + sq[i] * 8, &As[(wave * 128 + i * 64) * 8]);
      gl_lds16(Bm + (size_t)rb * K + k0 + sq[i] * 8, &Bs[(wave * 128 + i * 64) * 8]);
    }
    __syncthreads();  // vmcnt(0) drained by compiler before barrier

    short8 a[4], b[4];
#pragma unroll
    for (int i = 0; i < 4; ++i) {
      const int r = wm + i * 16 + l15;
      a[i] = *(const short8*)&As[(r * 4 + (quad ^ ((r >> 1) & 3))) * 8];
    }
#pragma unroll
    for (int j = 0; j < 4; ++j) {
      const int r = wn + j * 16 + l15;
      b[j] = *(const short8*)&Bs[(r * 4 + (quad ^ ((r >> 1) & 3))) * 8];
    }
#pragma unroll
    for (int i = 0; i < 4; ++i)
#pragma unroll
      for (int j = 0; j < 4; ++j)
        acc[i][j] = __builtin_amdgcn_mfma_f32_16x16x32_bf16(a[i], b[j], acc[i][j], 0, 0, 0);
  }

  // Epilogue: C/D layout col=lane&15, row=quad*4+reg (verified in R4/R5)
#pragma unroll
  for (int i = 0; i < 4; ++i) {
#pragma unroll
    for (int j = 0; j < 4; ++j) {
      const int col = n0 + wn + j * 16 + l15;
      if (col < N) {
#pragma unroll
        for (int r = 0; r < 4; ++r) {
          const int row = m0 + wm + i * 16 + quad * 4 + r;
          store_out(&C[(size_t)row * N + col], acc[i][j][r]);
        }
      }
    }
  }
}

// ---------------------------------------------------------------------------
// RMSNorm: fp32 in -> bf16 out (stats in fp32, matching reference chain)
// ---------------------------------------------------------------------------
__global__ __launch_bounds__(256) void rmsnorm_bf16(const float* __restrict__ x,
                                                    const float* __restrict__ w,
                                                    unsigned short* __restrict__ o, int n) {
  __shared__ float red[256];
  const int row = blockIdx.x;
  const float* p = x + (size_t)row * n;
  float s = 0.f;
  for (int i = threadIdx.x; i < n; i += 256) { float v = p[i]; s += v * v; }
  red[threadIdx.x] = s;
  __syncthreads();
  for (int off = 128; off > 0; off >>= 1) {
    if (threadIdx.x < off) red[threadIdx.x] += red[threadIdx.x + off];
    __syncthreads();
  }
  const float inv = rsqrtf(red[0] / (float)n + 1e-6f);
  unsigned short* po = o + (size_t)row * n;
  for (int i = threadIdx.x; i < n; i += 256) po[i] = f2bf(p[i] * inv * w[i]);
}

// ---------------------------------------------------------------------------
// Interleaved RoPE: fp32 in -> bf16 out. Layout (rows, heads*64); pos = row % S.
// ---------------------------------------------------------------------------
__global__ void rope_bf16(const float* __restrict__ xin, unsigned short* __restrict__ xout,
                          int heads, int total_pairs) {
  int idx = blockIdx.x * blockDim.x + threadIdx.x;
  if (idx >= total_pairs) return;
  const int i = idx & 31;
  const int h = (idx >> 5) % heads;
  const int row = idx / (32 * heads);
  const int pos = row & (S_ - 1);
  const float freq = expf(-9.210340371976184f * (float)i / 32.0f);
  const float ang = (float)pos * freq;
  const float c = cosf(ang), sn = sinf(ang);
  const float* p = xin + ((size_t)row * heads + h) * 64 + 2 * i;
  unsigned short* q = xout + ((size_t)row * heads + h) * 64 + 2 * i;
  const float x1 = p[0], x2 = p[1];
  q[0] = f2bf(x1 * c - x2 * sn);
  q[1] = f2bf(x1 * sn + x2 * c);
}

// ---------------------------------------------------------------------------
// MFMA flash attention, all-bf16 inputs, bf16 output.
// Block: 256 threads = 4 waves; Q-tile 64 rows, K-tiles of 64 keys.
// NOTE: attn_o aliases q_nope (same buffer). Safe: block (qt,h,b) reads its
// Q slice into registers in the prologue and writes the identical slice in
// the epilogue; no other block touches that slice. No __restrict__ on those.
// ---------------------------------------------------------------------------
#define LK 200   // Ks stride (192 + 8 pad), bf16 elems
#define LV 72    // Vt / Ps stride (64 + 8 pad), bf16 elems

__global__ __launch_bounds__(256) void flash_attn_mfma(const unsigned short* q_nope,
                                                       const unsigned short* __restrict__ q_pe,
                                                       const unsigned short* __restrict__ kv_up,
                                                       const unsigned short* __restrict__ k_rope,
                                                       unsigned short* attn_o) {
  __shared__ unsigned short Ks[64 * LK];   // 25.6 KB
  __shared__ unsigned short Vt[128 * LV];  // 18.4 KB (V transposed: feat x key)
  __shared__ unsigned short Ps[64 * LV];   //  9.2 KB

  const int tid  = threadIdx.x;
  const int wave = tid >> 6;
  const int lane = tid & 63;
  const int quad = lane >> 4;
  const int l15  = lane & 15;
  const int qt = blockIdx.x;
  const int q0 = qt * 64;
  const int h  = blockIdx.y;
  const int b  = blockIdx.z;
  const size_t tok0 = (size_t)b * S_;
  const float scale = 0.07216878364870323f;  // 1/sqrt(192)

  // Q fragments (A-layout): row = wave*16 + l15, k-chunks of 8 at quad*8
  short8 qf[6];
  {
    const size_t qrow = tok0 + q0 + wave * 16 + l15;
    const unsigned short* pn = q_nope + qrow * (size_t)(H_ * NOPE_) + h * NOPE_;
    const unsigned short* pp = q_pe + qrow * (size_t)(H_ * ROPE_) + h * ROPE_;
#pragma unroll
    for (int s = 0; s < 4; ++s) qf[s] = *(const short8*)(pn + s * 32 + quad * 8);
#pragma unroll
    for (int s = 4; s < 6; ++s) qf[s] = *(const short8*)(pp + (s - 4) * 32 + quad * 8);
  }

  float m_st[4], l_st[4];
#pragma unroll
  for (int r = 0; r < 4; ++r) { m_st[r] = -1e30f; l_st[r] = 0.f; }
  f32x4 o[8];
#pragma unroll
  for (int nt = 0; nt < 8; ++nt) { f32x4 z = {0.f, 0.f, 0.f, 0.f}; o[nt] = z; }

  for (int kt = 0; kt <= qt; ++kt) {
    const int k0 = kt * 64;
    __syncthreads();

    // stage K (64 x 192 bf16): 1536 16B-chunks, 6/thread
#pragma unroll
    for (int i = 0; i < 6; ++i) {
      const int u = i * 256 + tid;
      const int row = u / 24, c8 = u % 24;
      const size_t krow = tok0 + k0 + row;
      const unsigned short* src = (c8 < 16)
          ? (kv_up + krow * (size_t)(H_ * 256) + h * 256 + c8 * 8)
          : (k_rope + krow * (size_t)ROPE_ + (c8 - 16) * 8);
      *(uint4*)&Ks[row * LK + c8 * 8] = *(const uint4*)src;
    }
    // stage V transposed: key-pair kp, 8-feat group c8 -> 8 packed u32 writes
#pragma unroll
    for (int i = 0; i < 2; ++i) {
      const int u = i * 256 + tid;
      const int kp = u >> 4, c8 = u & 15;
      const unsigned short* p0 =
          kv_up + (tok0 + k0 + 2 * kp) * (size_t)(H_ * 256) + h * 256 + NOPE_ + c8 * 8;
      union { uint4 v; unsigned short s[8]; } r0, r1;
      r0.v = *(const uint4*)p0;
      r1.v = *(const uint4*)(p0 + H_ * 256);
#pragma unroll
      for (int j = 0; j < 8; ++j)
        *(unsigned*)&Vt[(c8 * 8 + j) * LV + 2 * kp] =
            (unsigned)r0.s[j] | ((unsigned)r1.s[j] << 16);
    }
    __syncthreads();

    // S = Q K^T (wave strip 16 x 64)
    f32x4 sacc[4];
#pragma unroll
    for (int nt = 0; nt < 4; ++nt) { f32x4 z = {0.f, 0.f, 0.f, 0.f}; sacc[nt] = z; }
#pragma unroll
    for (int s = 0; s < 6; ++s) {
#pragma unroll
      for (int nt = 0; nt < 4; ++nt) {
        short8 kb = *(const short8*)&Ks[(nt * 16 + l15) * LK + s * 32 + quad * 8];
        sacc[nt] = __builtin_amdgcn_mfma_f32_16x16x32_bf16(qf[s], kb, sacc[nt], 0, 0, 0);
      }
    }

    float sc[4][4];
#pragma unroll
    for (int nt = 0; nt < 4; ++nt)
#pragma unroll
      for (int r = 0; r < 4; ++r) {
        float v = sacc[nt][r] * scale;
        if (kt == qt && (nt * 16 + l15) > (wave * 16 + quad * 4 + r)) v = -1e30f;
        sc[nt][r] = v;
      }

    float mt[4];
#pragma unroll
    for (int r = 0; r < 4; ++r)
      mt[r] = fmaxf(fmaxf(sc[0][r], sc[1][r]), fmaxf(sc[2][r], sc[3][r]));
#pragma unroll
    for (int mask = 1; mask <= 8; mask <<= 1)
#pragma unroll
      for (int r = 0; r < 4; ++r) mt[r] = fmaxf(mt[r], __shfl_xor(mt[r], mask, 64));

    float al[4], rs[4];
#pragma unroll
    for (int r = 0; r < 4; ++r) {
      const float mn = fmaxf(m_st[r], mt[r]);
      al[r] = expf(m_st[r] - mn);
      m_st[r] = mn;
      rs[r] = 0.f;
    }
#pragma unroll
    for (int nt = 0; nt < 4; ++nt)
#pragma unroll
      for (int r = 0; r < 4; ++r) {
        const float p = expf(sc[nt][r] - m_st[r]);
        sc[nt][r] = p;
        rs[r] += p;
      }
#pragma unroll
    for (int mask = 1; mask <= 8; mask <<= 1)
#pragma unroll
      for (int r = 0; r < 4; ++r) rs[r] += __shfl_xor(rs[r], mask, 64);
#pragma unroll
    for (int r = 0; r < 4; ++r) l_st[r] = l_st[r] * al[r] + rs[r];

    // P: C-layout -> LDS (bf16) -> A-layout reads
#pragma unroll
    for (int nt = 0; nt < 4; ++nt)
#pragma unroll
      for (int r = 0; r < 4; ++r)
        Ps[(wave * 16 + quad * 4 + r) * LV + nt * 16 + l15] = f2bf(sc[nt][r]);
    __syncthreads();

    // O = O*alpha + P V
#pragma unroll
    for (int nt = 0; nt < 8; ++nt)
#pragma unroll
      for (int r = 0; r < 4; ++r) o[nt][r] *= al[r];
#pragma unroll
    for (int s = 0; s < 2; ++s) {
      short8 pa = *(const short8*)&Ps[(wave * 16 + l15) * LV + s * 32 + quad * 8];
#pragma unroll
      for (int nt = 0; nt < 8; ++nt) {
        short8 vb = *(const short8*)&Vt[(nt * 16 + l15) * LV + s * 32 + quad * 8];
        o[nt] = __builtin_amdgcn_mfma_f32_16x16x32_bf16(pa, vb, o[nt], 0, 0, 0);
      }
    }
  }

  float invl[4];
#pragma unroll
  for (int r = 0; r < 4; ++r) invl[r] = 1.f / l_st[r];
#pragma unroll
  for (int nt = 0; nt < 8; ++nt)
#pragma unroll
    for (int r = 0; r < 4; ++r) {
      const size_t row = tok0 + q0 + wave * 16 + quad * 4 + r;
      attn_o[row * (size_t)(H_ * VDIM_) + h * VDIM_ + nt * 16 + l15] = f2bf(o[nt][r] * invl[r]);
    }
}

// ---------------------------------------------------------------------------
// Launch
// ---------------------------------------------------------------------------
extern "C" void kernel_launch(void* const* d_in, const int* in_sizes, int n_in,
                              void* d_out, int out_size, void* d_ws, size_t ws_size,
                              hipStream_t stream) {
  (void)in_sizes; (void)n_in;
  const float* x         = (const float*)d_in[0];
  const float* wq_down   = (const float*)d_in[1];
  const float* q_norm_w  = (const float*)d_in[2];
  const float* wq_up     = (const float*)d_in[3];
  const float* wq_rope   = (const float*)d_in[4];
  const float* wkv_down  = (const float*)d_in[5];
  const float* kv_norm_w = (const float*)d_in[6];
  const float* wkv_up    = (const float*)d_in[7];
  const float* wk_rope   = (const float*)d_in[8];
  const float* wo        = (const float*)d_in[9];
  float* out = (float*)d_out;

  // ---- workspace carve (bytes). Total ~140.2 MB (< 145 MB proven available).
  const size_t SZ_XBF   = (size_t)TOK_ * DIM_ * 2;
  const size_t SZ_WQD   = (size_t)QR_ * DIM_ * 2;
  const size_t SZ_WKVD  = (size_t)KVR_ * DIM_ * 2;
  const size_t SZ_WKR   = (size_t)ROPE_ * DIM_ * 2;
  const size_t SZ_WQU   = (size_t)H_ * NOPE_ * QR_ * 2;
  const size_t SZ_WQR   = (size_t)H_ * ROPE_ * QR_ * 2;
  const size_t SZ_WKVU  = (size_t)H_ * (NOPE_ + VDIM_) * KVR_ * 2;
  const size_t SZ_WO    = (size_t)DIM_ * H_ * VDIM_ * 2;
  const size_t SZ_QC    = (size_t)TOK_ * QR_ * 4;        // also holds q_pe fp32 later
  const size_t SZ_KVC   = (size_t)TOK_ * KVR_ * 4;
  const size_t SZ_QCN   = (size_t)TOK_ * QR_ * 2;
  const size_t SZ_KVCN  = (size_t)TOK_ * KVR_ * 2;
  const size_t SZ_QNOPE = (size_t)TOK_ * H_ * NOPE_ * 2; // also holds attn_o bf16
  const size_t SZ_QPEB  = (size_t)TOK_ * H_ * ROPE_ * 2;
  const size_t SZ_KRF   = (size_t)TOK_ * ROPE_ * 4;
  const size_t SZ_KRB   = (size_t)TOK_ * ROPE_ * 2;
  const size_t SZ_KVUP  = (size_t)TOK_ * H_ * (NOPE_ + VDIM_) * 2;
  const size_t NEED = SZ_XBF + SZ_WQD + SZ_WKVD + SZ_WKR + SZ_WQU + SZ_WQR + SZ_WKVU +
                      SZ_WO + SZ_QC + SZ_KVC + SZ_QCN + SZ_KVCN + SZ_QNOPE + SZ_QPEB +
                      SZ_KRF + SZ_KRB + SZ_KVUP;
  if (ws_size < NEED) {
    hipMemsetAsync(d_out, 0, (size_t)out_size * sizeof(float), stream);
    return;
  }
  char* p = (char*)d_ws;
  unsigned short* x_bf    = (unsigned short*)p; p += SZ_XBF;
  unsigned short* wqd_bf  = (unsigned short*)p; p += SZ_WQD;
  unsigned short* wkvd_bf = (unsigned short*)p; p += SZ_WKVD;
  unsigned short* wkr_bf  = (unsigned short*)p; p += SZ_WKR;
  unsigned short* wqu_bf  = (unsigned short*)p; p += SZ_WQU;
  unsigned short* wqr_bf  = (unsigned short*)p; p += SZ_WQR;
  unsigned short* wkvu_bf = (unsigned short*)p; p += SZ_WKVU;
  unsigned short* wo_bf   = (unsigned short*)p; p += SZ_WO;
  float*          q_c     = (float*)p;          p += SZ_QC;   // alias: q_pe fp32
  float*          kv_c    = (float*)p;          p += SZ_KVC;
  unsigned short* q_cn    = (unsigned short*)p; p += SZ_QCN;
  unsigned short* kv_cn   = (unsigned short*)p; p += SZ_KVCN;
  unsigned short* q_nope  = (unsigned short*)p; p += SZ_QNOPE; // alias: attn_o bf16
  unsigned short* q_pe_bf = (unsigned short*)p; p += SZ_QPEB;
  float*          k_ropef = (float*)p;          p += SZ_KRF;
  unsigned short* k_ropeb = (unsigned short*)p; p += SZ_KRB;
  unsigned short* kv_upbf = (unsigned short*)p; p += SZ_KVUP;
  float*          q_pe_f  = q_c;        // q_c dead after rmsnorm
  unsigned short* attn_o  = q_nope;     // q_nope dead after flash (in-block R-then-W)

  const dim3 blk(256);
  // ---- one-time bf16 casts (x + all weights)
  cvt_bf16<<<(TOK_ * DIM_ / 8 + 255) / 256, blk, 0, stream>>>(x, x_bf, TOK_ * DIM_ / 8);
  cvt_bf16<<<(QR_ * DIM_ / 8 + 255) / 256, blk, 0, stream>>>(wq_down, wqd_bf, QR_ * DIM_ / 8);
  cvt_bf16<<<(KVR_ * DIM_ / 8 + 255) / 256, blk, 0, stream>>>(wkv_down, wkvd_bf, KVR_ * DIM_ / 8);
  cvt_bf16<<<(ROPE_ * DIM_ / 8 + 255) / 256, blk, 0, stream>>>(wk_rope, wkr_bf, ROPE_ * DIM_ / 8);
  cvt_bf16<<<(H_ * NOPE_ * QR_ / 8 + 255) / 256, blk, 0, stream>>>(wq_up, wqu_bf, H_ * NOPE_ * QR_ / 8);
  cvt_bf16<<<(H_ * ROPE_ * QR_ / 8 + 255) / 256, blk, 0, stream>>>(wq_rope, wqr_bf, H_ * ROPE_ * QR_ / 8);
  cvt_bf16<<<(H_ * (NOPE_ + VDIM_) * KVR_ / 8 + 255) / 256, blk, 0, stream>>>(wkv_up, wkvu_bf,
                                                                              H_ * (NOPE_ + VDIM_) * KVR_ / 8);
  cvt_bf16<<<(DIM_ * H_ * VDIM_ / 8 + 255) / 256, blk, 0, stream>>>(wo, wo_bf, DIM_ * H_ * VDIM_ / 8);

  // ---- down projections (fp32 out for norm fidelity; k_rope fp32 for rope)
  gemm_bf16<float><<<dim3(QR_ / 128, TOK_ / 128), blk, 0, stream>>>(x_bf, wqd_bf, q_c, TOK_, QR_, DIM_);
  gemm_bf16<float><<<dim3(KVR_ / 128, TOK_ / 128), blk, 0, stream>>>(x_bf, wkvd_bf, kv_c, TOK_, KVR_, DIM_);
  gemm_bf16<float><<<dim3(1, TOK_ / 128), blk, 0, stream>>>(x_bf, wkr_bf, k_ropef, TOK_, ROPE_, DIM_);

  // ---- RMSNorms (fp32 stats, bf16 out)
  rmsnorm_bf16<<<TOK_, blk, 0, stream>>>(q_c, q_norm_w, q_cn, QR_);
  rmsnorm_bf16<<<TOK_, blk, 0, stream>>>(kv_c, kv_norm_w, kv_cn, KVR_);

  // ---- up projections (q_nope/kv_up direct to bf16; q_pe fp32 for rope)
  gemm_bf16<unsigned short><<<dim3(H_ * NOPE_ / 128, TOK_ / 128), blk, 0, stream>>>(
      q_cn, wqu_bf, q_nope, TOK_, H_ * NOPE_, QR_);
  gemm_bf16<float><<<dim3(H_ * ROPE_ / 128, TOK_ / 128), blk, 0, stream>>>(
      q_cn, wqr_bf, q_pe_f, TOK_, H_ * ROPE_, QR_);
  gemm_bf16<unsigned short><<<dim3(H_ * (NOPE_ + VDIM_) / 128, TOK_ / 128), blk, 0, stream>>>(
      kv_cn, wkvu_bf, kv_upbf, TOK_, H_ * (NOPE_ + VDIM_), KVR_);

  // ---- RoPE (fp32 -> bf16)
  {
    const int pairs_q = TOK_ * H_ * 32;
    rope_bf16<<<(pairs_q + 255) / 256, blk, 0, stream>>>(q_pe_f, q_pe_bf, H_, pairs_q);
    const int pairs_k = TOK_ * 32;
    rope_bf16<<<(pairs_k + 255) / 256, blk, 0, stream>>>(k_ropef, k_ropeb, 1, pairs_k);
  }

  // ---- attention (bf16 in/out; attn_o aliases q_nope)
  flash_attn_mfma<<<dim3(S_ / 64, H_, B_), blk, 0, stream>>>(q_nope, q_pe_bf, kv_upbf, k_ropeb, attn_o);

  // ---- output projection
  gemm_bf16<float><<<dim3(DIM_ / 128, TOK_ / 128), blk, 0, stream>>>(attn_o, wo_bf, out, TOK_, DIM_, H_ * VDIM_);
}

// Round 7
// 659.110 us; speedup vs baseline: 7.5764x; 1.1929x over previous
//
#include <hip/hip_runtime.h>
#include <hip/hip_bf16.h>
#include <math.h>

// Problem constants (from reference)
#define B_    2
#define S_    2048
#define DIM_  2048
#define H_    16
#define NOPE_ 128
#define ROPE_ 64
#define VDIM_ 128
#define QR_   1024
#define KVR_  512
#define TOK_  (B_ * S_)   // 4096 token rows

typedef __attribute__((ext_vector_type(8))) short short8;   // 8 bf16 (4 VGPRs)
typedef __attribute__((ext_vector_type(4))) float f32x4;    // MFMA acc

// fp32 -> bf16 (round-to-nearest-even), raw ushort
__device__ __forceinline__ unsigned short f2bf(float f) {
  union { float f; unsigned u; } v; v.f = f;
  unsigned r = v.u + 0x7fffu + ((v.u >> 16) & 1u);
  return (unsigned short)(r >> 16);
}
__device__ __forceinline__ unsigned pk2(float lo, float hi) {
  return (unsigned)f2bf(lo) | ((unsigned)f2bf(hi) << 16);
}

// async global->LDS, 16 B per lane; dest = wave-uniform base + lane*16.
__device__ __forceinline__ void gl_lds16(const unsigned short* g, unsigned short* lds_base) {
  __builtin_amdgcn_global_load_lds(
      (const __attribute__((address_space(1))) void*)g,
      (__attribute__((address_space(3))) void*)lds_base,
      16, 0, 0);
}

__device__ __forceinline__ void store_out(float* p, float v) { *p = v; }
__device__ __forceinline__ void store_out(unsigned short* p, float v) { *p = f2bf(v); }

// ---------------------------------------------------------------------------
// fp32 -> bf16 bulk cast. n8 = elements/8.
// ---------------------------------------------------------------------------
__global__ __launch_bounds__(256) void cvt_bf16(const float* __restrict__ in,
                                                unsigned short* __restrict__ o, int n8) {
  const int idx = blockIdx.x * 256 + threadIdx.x;
  if (idx >= n8) return;
  float4 f0 = *(const float4*)(in + (size_t)idx * 8);
  float4 f1 = *(const float4*)(in + (size_t)idx * 8 + 4);
  uint4 u;
  u.x = pk2(f0.x, f0.y); u.y = pk2(f0.z, f0.w);
  u.z = pk2(f1.x, f1.y); u.w = pk2(f1.z, f1.w);
  *(uint4*)&o[(size_t)idx * 8] = u;
}

// ---------------------------------------------------------------------------
// MFMA GEMM: C[M x N] = A[M x K] @ B[N x K]^T. bf16 in, OutT out.
// Tile 128 x (NT*32), BK=32, 256 threads = 4 waves; wave does 64 x (NT*16).
// NT=4 -> 128-wide tile (default); NT=2 -> 64-wide (narrow-N GEMMs: doubles
// block count so small-N shapes still fill 256 CUs).
// Staging: global_load_lds w16 into XOR-swizzled no-pad LDS (R6-verified).
// ---------------------------------------------------------------------------
template <typename OutT, int NT>
__global__ __launch_bounds__(256) void gemm_bf16(const unsigned short* __restrict__ A,
                                                 const unsigned short* __restrict__ Bm,
                                                 OutT* __restrict__ C,
                                                 int M, int N, int K) {
  constexpr int BN = NT * 32;
  __shared__ unsigned short As[128 * 32];
  __shared__ unsigned short Bs[BN * 32];
  const int tid  = threadIdx.x;
  const int wave = tid >> 6;
  const int lane = tid & 63;
  const int quad = lane >> 4;
  const int l15  = lane & 15;
  const int m0 = blockIdx.y * 128;
  const int n0 = blockIdx.x * BN;
  const int wm = (wave & 1) * 64;
  const int wn = (wave >> 1) * (NT * 16);

  f32x4 acc[4][NT];
#pragma unroll
  for (int i = 0; i < 4; ++i)
#pragma unroll
    for (int j = 0; j < NT; ++j) {
      f32x4 z = {0.f, 0.f, 0.f, 0.f};
      acc[i][j] = z;
    }

  for (int k0 = 0; k0 < K; k0 += 32) {
    __syncthreads();
    // A: 512 chunk-slots, 2/thread
#pragma unroll
    for (int i = 0; i < 2; ++i) {
      const int s = i * 256 + tid;
      const int srow = s >> 2;
      const int sq = (s & 3) ^ ((srow >> 1) & 3);
      gl_lds16(A + (size_t)(m0 + srow) * K + k0 + sq * 8, &As[(i * 256 + wave * 64) * 8]);
    }
    // B: BN*4 chunk-slots
#pragma unroll
    for (int i = 0; i < BN / 64; ++i) {
      const int s = i * 256 + tid;
      const int srow = s >> 2;
      const int sq = (s & 3) ^ ((srow >> 1) & 3);
      const int rb = min(n0 + srow, N - 1);
      gl_lds16(Bm + (size_t)rb * K + k0 + sq * 8, &Bs[(i * 256 + wave * 64) * 8]);
    }
    __syncthreads();

    short8 a[4], b[NT];
#pragma unroll
    for (int i = 0; i < 4; ++i) {
      const int r = wm + i * 16 + l15;
      a[i] = *(const short8*)&As[(r * 4 + (quad ^ ((r >> 1) & 3))) * 8];
    }
#pragma unroll
    for (int j = 0; j < NT; ++j) {
      const int r = wn + j * 16 + l15;
      b[j] = *(const short8*)&Bs[(r * 4 + (quad ^ ((r >> 1) & 3))) * 8];
    }
#pragma unroll
    for (int i = 0; i < 4; ++i)
#pragma unroll
      for (int j = 0; j < NT; ++j)
        acc[i][j] = __builtin_amdgcn_mfma_f32_16x16x32_bf16(a[i], b[j], acc[i][j], 0, 0, 0);
  }

#pragma unroll
  for (int i = 0; i < 4; ++i) {
#pragma unroll
    for (int j = 0; j < NT; ++j) {
      const int col = n0 + wn + j * 16 + l15;
      if (col < N) {
#pragma unroll
        for (int r = 0; r < 4; ++r) {
          const int row = m0 + wm + i * 16 + quad * 4 + r;
          store_out(&C[(size_t)row * N + col], acc[i][j][r]);
        }
      }
    }
  }
}

// ---------------------------------------------------------------------------
// RMSNorm: fp32 in -> bf16 out
// ---------------------------------------------------------------------------
__global__ __launch_bounds__(256) void rmsnorm_bf16(const float* __restrict__ x,
                                                    const float* __restrict__ w,
                                                    unsigned short* __restrict__ o, int n) {
  __shared__ float red[256];
  const int row = blockIdx.x;
  const float* p = x + (size_t)row * n;
  float s = 0.f;
  for (int i = threadIdx.x; i < n; i += 256) { float v = p[i]; s += v * v; }
  red[threadIdx.x] = s;
  __syncthreads();
  for (int off = 128; off > 0; off >>= 1) {
    if (threadIdx.x < off) red[threadIdx.x] += red[threadIdx.x + off];
    __syncthreads();
  }
  const float inv = rsqrtf(red[0] / (float)n + 1e-6f);
  unsigned short* po = o + (size_t)row * n;
  for (int i = threadIdx.x; i < n; i += 256) po[i] = f2bf(p[i] * inv * w[i]);
}

// ---------------------------------------------------------------------------
// Interleaved RoPE: fp32 in -> bf16 out. Layout (rows, heads*64); pos = row % S.
// ---------------------------------------------------------------------------
__global__ void rope_bf16(const float* __restrict__ xin, unsigned short* __restrict__ xout,
                          int heads, int total_pairs) {
  int idx = blockIdx.x * blockDim.x + threadIdx.x;
  if (idx >= total_pairs) return;
  const int i = idx & 31;
  const int h = (idx >> 5) % heads;
  const int row = idx / (32 * heads);
  const int pos = row & (S_ - 1);
  const float freq = expf(-9.210340371976184f * (float)i / 32.0f);
  const float ang = (float)pos * freq;
  const float c = cosf(ang), sn = sinf(ang);
  const float* p = xin + ((size_t)row * heads + h) * 64 + 2 * i;
  unsigned short* q = xout + ((size_t)row * heads + h) * 64 + 2 * i;
  const float x1 = p[0], x2 = p[1];
  q[0] = f2bf(x1 * c - x2 * sn);
  q[1] = f2bf(x1 * sn + x2 * c);
}

// ---------------------------------------------------------------------------
// One-shot V transpose: kv_up V-part [tok][h*256+128..256) -> vt_g[b][h][feat][key]
// (bit-exact copy; hoists the per-tile transpose out of the flash K-loop)
// ---------------------------------------------------------------------------
__global__ __launch_bounds__(256) void transpose_v(const unsigned short* __restrict__ kv_up,
                                                   unsigned short* __restrict__ vt_g) {
  __shared__ unsigned short T[128 * 72];
  const int tid = threadIdx.x;
  const int k0 = blockIdx.x * 64;
  const int h = blockIdx.y, b = blockIdx.z;
  const size_t tok0 = (size_t)b * S_;
#pragma unroll
  for (int i = 0; i < 2; ++i) {
    const int u = i * 256 + tid;           // 512 units: key-pair kp, 8-feat group c8
    const int kp = u >> 4, c8 = u & 15;
    const unsigned short* p0 =
        kv_up + (tok0 + k0 + 2 * kp) * (size_t)(H_ * 256) + h * 256 + NOPE_ + c8 * 8;
    union { uint4 v; unsigned short s[8]; } r0, r1;
    r0.v = *(const uint4*)p0;
    r1.v = *(const uint4*)(p0 + H_ * 256);
#pragma unroll
    for (int j = 0; j < 8; ++j)
      *(unsigned*)&T[(c8 * 8 + j) * 72 + 2 * kp] = (unsigned)r0.s[j] | ((unsigned)r1.s[j] << 16);
  }
  __syncthreads();
#pragma unroll
  for (int i = 0; i < 4; ++i) {
    const int sl = i * 256 + tid;          // 1024 out-chunks
    const int f = sl >> 3, c = sl & 7;
    *(uint4*)(vt_g + ((size_t)(b * H_ + h) * 128 + f) * S_ + k0 + c * 8) =
        *(const uint4*)&T[f * 72 + c * 8];
  }
}

// ---------------------------------------------------------------------------
// MFMA flash attention, balanced-pair schedule.
// Block = pair i: processes q-tiles {31-i, i} -> exactly 33 K-tile iterations
// for every block (kills the 1:32 causal imbalance seen in R6).
// All staging via global_load_lds w16, XOR-swizzled sources; V comes
// pre-transposed from vt_g. 2 __syncthreads per tile; Ps round-trip is
// wave-private (same-wave DS ordering + wave_barrier, no block barrier).
// attn_o aliases q_nope: block writes rows/cols it alone reads (h-disjoint).
// ---------------------------------------------------------------------------
#define LV 72    // Ps stride (64 + 8 pad)

__global__ __launch_bounds__(256) void flash_attn_mfma(const unsigned short* q_nope,
                                                       const unsigned short* __restrict__ q_pe,
                                                       const unsigned short* __restrict__ kv_up,
                                                       const unsigned short* __restrict__ k_rope,
                                                       const unsigned short* __restrict__ vt_g,
                                                       unsigned short* attn_o) {
  __shared__ unsigned short Ksn[64 * 16 * 8];  // 16 KB keys x 128 nope-feats (swizzled)
  __shared__ unsigned short Ksr[64 * 8 * 8];   //  8 KB keys x 64 rope-feats (swizzled)
  __shared__ unsigned short Vt[128 * 8 * 8];   // 16 KB feats x 64 keys (swizzled)
  __shared__ unsigned short Ps[64 * LV];       //  9 KB

  const int tid  = threadIdx.x;
  const int wave = tid >> 6;
  const int lane = tid & 63;
  const int quad = lane >> 4;
  const int l15  = lane & 15;
  const int pair = blockIdx.x;   // 0..15
  const int h  = blockIdx.y;
  const int b  = blockIdx.z;
  const size_t tok0 = (size_t)b * S_;
  const float scale = 0.07216878364870323f;  // 1/sqrt(192)

#pragma unroll
  for (int ph = 0; ph < 2; ++ph) {
    const int qt = ph ? pair : (31 - pair);
    const int q0 = qt * 64;

    // Q fragments (A-layout): row = wave*16 + l15
    short8 qf[6];
    {
      const size_t qrow = tok0 + q0 + wave * 16 + l15;
      const unsigned short* pn = q_nope + qrow * (size_t)(H_ * NOPE_) + h * NOPE_;
      const unsigned short* pp = q_pe + qrow * (size_t)(H_ * ROPE_) + h * ROPE_;
#pragma unroll
      for (int s = 0; s < 4; ++s) qf[s] = *(const short8*)(pn + s * 32 + quad * 8);
#pragma unroll
      for (int s = 4; s < 6; ++s) qf[s] = *(const short8*)(pp + (s - 4) * 32 + quad * 8);
    }

    float m_st[4], l_st[4];
#pragma unroll
    for (int r = 0; r < 4; ++r) { m_st[r] = -1e30f; l_st[r] = 0.f; }
    f32x4 o[8];
#pragma unroll
    for (int nt = 0; nt < 8; ++nt) { f32x4 z = {0.f, 0.f, 0.f, 0.f}; o[nt] = z; }

    for (int kt = 0; kt <= qt; ++kt) {
      const int k0 = kt * 64;
      __syncthreads();  // prior tile's (and prior phase's) LDS reads complete

      // --- stage K-nope: 1024 chunk-slots; slot = key*16 + (c ^ (key&15)) ---
#pragma unroll
      for (int i = 0; i < 4; ++i) {
        const int sl = i * 256 + tid;
        const int key = sl >> 4;
        const int c = (sl & 15) ^ (key & 15);
        gl_lds16(kv_up + (tok0 + k0 + key) * (size_t)(H_ * 256) + h * 256 + c * 8,
                 &Ksn[(i * 256 + wave * 64) * 8]);
      }
      // --- stage K-rope: 512 slots; slot = key*8 + (c ^ (key&7)) ---
#pragma unroll
      for (int i = 0; i < 2; ++i) {
        const int sl = i * 256 + tid;
        const int key = sl >> 3;
        const int c = (sl & 7) ^ (key & 7);
        gl_lds16(k_rope + (tok0 + k0 + key) * (size_t)ROPE_ + c * 8,
                 &Ksr[(i * 256 + wave * 64) * 8]);
      }
      // --- stage V^T: 1024 slots; slot = f*8 + (c ^ (f&7)) ---
#pragma unroll
      for (int i = 0; i < 4; ++i) {
        const int sl = i * 256 + tid;
        const int f = sl >> 3;
        const int c = (sl & 7) ^ (f & 7);
        gl_lds16(vt_g + ((size_t)(b * H_ + h) * 128 + f) * S_ + k0 + c * 8,
                 &Vt[(i * 256 + wave * 64) * 8]);
      }
      __syncthreads();  // compiler drains vmcnt before barrier

      // --- S = Q K^T (wave strip 16 x 64) ---
      f32x4 sacc[4];
#pragma unroll
      for (int nt = 0; nt < 4; ++nt) { f32x4 z = {0.f, 0.f, 0.f, 0.f}; sacc[nt] = z; }
#pragma unroll
      for (int s = 0; s < 4; ++s) {
#pragma unroll
        for (int nt = 0; nt < 4; ++nt) {
          const int key = nt * 16 + l15;
          short8 kb = *(const short8*)&Ksn[(key * 16 + ((s * 4 + quad) ^ (key & 15))) * 8];
          sacc[nt] = __builtin_amdgcn_mfma_f32_16x16x32_bf16(qf[s], kb, sacc[nt], 0, 0, 0);
        }
      }
#pragma unroll
      for (int s = 4; s < 6; ++s) {
#pragma unroll
        for (int nt = 0; nt < 4; ++nt) {
          const int key = nt * 16 + l15;
          short8 kb = *(const short8*)&Ksr[(key * 8 + (((s - 4) * 4 + quad) ^ (key & 7))) * 8];
          sacc[nt] = __builtin_amdgcn_mfma_f32_16x16x32_bf16(qf[s], kb, sacc[nt], 0, 0, 0);
        }
      }

      float sc[4][4];
#pragma unroll
      for (int nt = 0; nt < 4; ++nt)
#pragma unroll
        for (int r = 0; r < 4; ++r) {
          float v = sacc[nt][r] * scale;
          if (kt == qt && (nt * 16 + l15) > (wave * 16 + quad * 4 + r)) v = -1e30f;
          sc[nt][r] = v;
        }

      float mt[4];
#pragma unroll
      for (int r = 0; r < 4; ++r)
        mt[r] = fmaxf(fmaxf(sc[0][r], sc[1][r]), fmaxf(sc[2][r], sc[3][r]));
#pragma unroll
      for (int mask = 1; mask <= 8; mask <<= 1)
#pragma unroll
        for (int r = 0; r < 4; ++r) mt[r] = fmaxf(mt[r], __shfl_xor(mt[r], mask, 64));

      float al[4], rs[4];
#pragma unroll
      for (int r = 0; r < 4; ++r) {
        const float mn = fmaxf(m_st[r], mt[r]);
        al[r] = expf(m_st[r] - mn);
        m_st[r] = mn;
        rs[r] = 0.f;
      }
#pragma unroll
      for (int nt = 0; nt < 4; ++nt)
#pragma unroll
        for (int r = 0; r < 4; ++r) {
          const float p = expf(sc[nt][r] - m_st[r]);
          sc[nt][r] = p;
          rs[r] += p;
        }
#pragma unroll
      for (int mask = 1; mask <= 8; mask <<= 1)
#pragma unroll
        for (int r = 0; r < 4; ++r) rs[r] += __shfl_xor(rs[r], mask, 64);
#pragma unroll
      for (int r = 0; r < 4; ++r) l_st[r] = l_st[r] * al[r] + rs[r];

      // --- P transpose via LDS (wave-private rows; no block barrier needed) ---
#pragma unroll
      for (int nt = 0; nt < 4; ++nt)
#pragma unroll
        for (int r = 0; r < 4; ++r)
          Ps[(wave * 16 + quad * 4 + r) * LV + nt * 16 + l15] = f2bf(sc[nt][r]);
      __builtin_amdgcn_wave_barrier();  // pin order; same-wave DS ops complete in order

      // --- O = O*alpha + P V ---
#pragma unroll
      for (int nt = 0; nt < 8; ++nt)
#pragma unroll
        for (int r = 0; r < 4; ++r) o[nt][r] *= al[r];
#pragma unroll
      for (int s = 0; s < 2; ++s) {
        short8 pa = *(const short8*)&Ps[(wave * 16 + l15) * LV + s * 32 + quad * 8];
#pragma unroll
        for (int nt = 0; nt < 8; ++nt) {
          const int f = nt * 16 + l15;
          short8 vb = *(const short8*)&Vt[(f * 8 + ((s * 4 + quad) ^ (f & 7))) * 8];
          o[nt] = __builtin_amdgcn_mfma_f32_16x16x32_bf16(pa, vb, o[nt], 0, 0, 0);
        }
      }
    }

    float invl[4];
#pragma unroll
    for (int r = 0; r < 4; ++r) invl[r] = 1.f / l_st[r];
#pragma unroll
    for (int nt = 0; nt < 8; ++nt)
#pragma unroll
      for (int r = 0; r < 4; ++r) {
        const size_t row = tok0 + q0 + wave * 16 + quad * 4 + r;
        attn_o[row * (size_t)(H_ * VDIM_) + h * VDIM_ + nt * 16 + l15] = f2bf(o[nt][r] * invl[r]);
      }
  }
}

// ---------------------------------------------------------------------------
// Launch
// ---------------------------------------------------------------------------
extern "C" void kernel_launch(void* const* d_in, const int* in_sizes, int n_in,
                              void* d_out, int out_size, void* d_ws, size_t ws_size,
                              hipStream_t stream) {
  (void)in_sizes; (void)n_in;
  const float* x         = (const float*)d_in[0];
  const float* wq_down   = (const float*)d_in[1];
  const float* q_norm_w  = (const float*)d_in[2];
  const float* wq_up     = (const float*)d_in[3];
  const float* wq_rope   = (const float*)d_in[4];
  const float* wkv_down  = (const float*)d_in[5];
  const float* kv_norm_w = (const float*)d_in[6];
  const float* wkv_up    = (const float*)d_in[7];
  const float* wk_rope   = (const float*)d_in[8];
  const float* wo        = (const float*)d_in[9];
  float* out = (float*)d_out;

  // ---- workspace carve (identical NEED to the R6 passing run: ~140.2 MB)
  const size_t SZ_XBF   = (size_t)TOK_ * DIM_ * 2;
  const size_t SZ_WQD   = (size_t)QR_ * DIM_ * 2;
  const size_t SZ_WKVD  = (size_t)KVR_ * DIM_ * 2;
  const size_t SZ_WKR   = (size_t)ROPE_ * DIM_ * 2;
  const size_t SZ_WQU   = (size_t)H_ * NOPE_ * QR_ * 2;
  const size_t SZ_WQR   = (size_t)H_ * ROPE_ * QR_ * 2;
  const size_t SZ_WKVU  = (size_t)H_ * (NOPE_ + VDIM_) * KVR_ * 2;
  const size_t SZ_WO    = (size_t)DIM_ * H_ * VDIM_ * 2;
  const size_t SZ_QC    = (size_t)TOK_ * QR_ * 4;   // aliases: q_pe fp32, then vt_g
  const size_t SZ_KVC   = (size_t)TOK_ * KVR_ * 4;
  const size_t SZ_QCN   = (size_t)TOK_ * QR_ * 2;
  const size_t SZ_KVCN  = (size_t)TOK_ * KVR_ * 2;
  const size_t SZ_QNOPE = (size_t)TOK_ * H_ * NOPE_ * 2; // aliases attn_o bf16
  const size_t SZ_QPEB  = (size_t)TOK_ * H_ * ROPE_ * 2;
  const size_t SZ_KRF   = (size_t)TOK_ * ROPE_ * 4;
  const size_t SZ_KRB   = (size_t)TOK_ * ROPE_ * 2;
  const size_t SZ_KVUP  = (size_t)TOK_ * H_ * (NOPE_ + VDIM_) * 2;
  const size_t NEED = SZ_XBF + SZ_WQD + SZ_WKVD + SZ_WKR + SZ_WQU + SZ_WQR + SZ_WKVU +
                      SZ_WO + SZ_QC + SZ_KVC + SZ_QCN + SZ_KVCN + SZ_QNOPE + SZ_QPEB +
                      SZ_KRF + SZ_KRB + SZ_KVUP;
  if (ws_size < NEED) {
    hipMemsetAsync(d_out, 0, (size_t)out_size * sizeof(float), stream);
    return;
  }
  char* p = (char*)d_ws;
  unsigned short* x_bf    = (unsigned short*)p; p += SZ_XBF;
  unsigned short* wqd_bf  = (unsigned short*)p; p += SZ_WQD;
  unsigned short* wkvd_bf = (unsigned short*)p; p += SZ_WKVD;
  unsigned short* wkr_bf  = (unsigned short*)p; p += SZ_WKR;
  unsigned short* wqu_bf  = (unsigned short*)p; p += SZ_WQU;
  unsigned short* wqr_bf  = (unsigned short*)p; p += SZ_WQR;
  unsigned short* wkvu_bf = (unsigned short*)p; p += SZ_WKVU;
  unsigned short* wo_bf   = (unsigned short*)p; p += SZ_WO;
  float*          q_c     = (float*)p;          p += SZ_QC;
  float*          kv_c    = (float*)p;          p += SZ_KVC;
  unsigned short* q_cn    = (unsigned short*)p; p += SZ_QCN;
  unsigned short* kv_cn   = (unsigned short*)p; p += SZ_KVCN;
  unsigned short* q_nope  = (unsigned short*)p; p += SZ_QNOPE;
  unsigned short* q_pe_bf = (unsigned short*)p; p += SZ_QPEB;
  float*          k_ropef = (float*)p;          p += SZ_KRF;
  unsigned short* k_ropeb = (unsigned short*)p; p += SZ_KRB;
  unsigned short* kv_upbf = (unsigned short*)p; p += SZ_KVUP;
  float*          q_pe_f  = q_c;                   // q_c dead after rmsnorm
  unsigned short* vt_g    = (unsigned short*)q_c;  // q_pe_f dead after rope_q (16.78 MB == needed)
  unsigned short* attn_o  = q_nope;                // q_nope dead after flash

  const dim3 blk(256);
  // ---- one-time bf16 casts
  cvt_bf16<<<(TOK_ * DIM_ / 8 + 255) / 256, blk, 0, stream>>>(x, x_bf, TOK_ * DIM_ / 8);
  cvt_bf16<<<(QR_ * DIM_ / 8 + 255) / 256, blk, 0, stream>>>(wq_down, wqd_bf, QR_ * DIM_ / 8);
  cvt_bf16<<<(KVR_ * DIM_ / 8 + 255) / 256, blk, 0, stream>>>(wkv_down, wkvd_bf, KVR_ * DIM_ / 8);
  cvt_bf16<<<(ROPE_ * DIM_ / 8 + 255) / 256, blk, 0, stream>>>(wk_rope, wkr_bf, ROPE_ * DIM_ / 8);
  cvt_bf16<<<(H_ * NOPE_ * QR_ / 8 + 255) / 256, blk, 0, stream>>>(wq_up, wqu_bf, H_ * NOPE_ * QR_ / 8);
  cvt_bf16<<<(H_ * ROPE_ * QR_ / 8 + 255) / 256, blk, 0, stream>>>(wq_rope, wqr_bf, H_ * ROPE_ * QR_ / 8);
  cvt_bf16<<<(H_ * (NOPE_ + VDIM_) * KVR_ / 8 + 255) / 256, blk, 0, stream>>>(wkv_up, wkvu_bf,
                                                                              H_ * (NOPE_ + VDIM_) * KVR_ / 8);
  cvt_bf16<<<(DIM_ * H_ * VDIM_ / 8 + 255) / 256, blk, 0, stream>>>(wo, wo_bf, DIM_ * H_ * VDIM_ / 8);

  // ---- down projections
  gemm_bf16<float, 4><<<dim3(QR_ / 128, TOK_ / 128), blk, 0, stream>>>(x_bf, wqd_bf, q_c, TOK_, QR_, DIM_);
  gemm_bf16<float, 2><<<dim3(KVR_ / 64, TOK_ / 128), blk, 0, stream>>>(x_bf, wkvd_bf, kv_c, TOK_, KVR_, DIM_);
  gemm_bf16<float, 2><<<dim3(1, TOK_ / 128), blk, 0, stream>>>(x_bf, wkr_bf, k_ropef, TOK_, ROPE_, DIM_);

  // ---- RMSNorms
  rmsnorm_bf16<<<TOK_, blk, 0, stream>>>(q_c, q_norm_w, q_cn, QR_);
  rmsnorm_bf16<<<TOK_, blk, 0, stream>>>(kv_c, kv_norm_w, kv_cn, KVR_);

  // ---- up projections
  gemm_bf16<unsigned short, 4><<<dim3(H_ * NOPE_ / 128, TOK_ / 128), blk, 0, stream>>>(
      q_cn, wqu_bf, q_nope, TOK_, H_ * NOPE_, QR_);
  gemm_bf16<float, 4><<<dim3(H_ * ROPE_ / 128, TOK_ / 128), blk, 0, stream>>>(
      q_cn, wqr_bf, q_pe_f, TOK_, H_ * ROPE_, QR_);
  gemm_bf16<unsigned short, 4><<<dim3(H_ * (NOPE_ + VDIM_) / 128, TOK_ / 128), blk, 0, stream>>>(
      kv_cn, wkvu_bf, kv_upbf, TOK_, H_ * (NOPE_ + VDIM_), KVR_);

  // ---- RoPE (q first: frees q_c region for vt_g)
  {
    const int pairs_q = TOK_ * H_ * 32;
    rope_bf16<<<(pairs_q + 255) / 256, blk, 0, stream>>>(q_pe_f, q_pe_bf, H_, pairs_q);
    const int pairs_k = TOK_ * 32;
    rope_bf16<<<(pairs_k + 255) / 256, blk, 0, stream>>>(k_ropef, k_ropeb, 1, pairs_k);
  }

  // ---- V transpose (after rope_q; vt_g aliases q_c region)
  transpose_v<<<dim3(S_ / 64, H_, B_), blk, 0, stream>>>(kv_upbf, vt_g);

  // ---- attention (balanced pairs: grid.x = 16)
  flash_attn_mfma<<<dim3(16, H_, B_), blk, 0, stream>>>(q_nope, q_pe_bf, kv_upbf, k_ropeb, vt_g, attn_o);

  // ---- output projection
  gemm_bf16<float, 4><<<dim3(DIM_ / 128, TOK_ / 128), blk, 0, stream>>>(attn_o, wo_bf, out, TOK_, DIM_, H_ * VDIM_);
}